// Round 1
// baseline (1295.950 us; speedup 1.0000x reference)
//
#include <hip/hip_runtime.h>
#include <math.h>

// ---------------- problem constants ----------------
constexpr int B_    = 64;
constexpr int C_    = 192;
constexpr int N_    = 576;    // nodes per image (24x24)
constexpr int BN_   = B_ * N_;      // 36864
constexpr int K_    = 5;
constexpr int E_    = BN_ * K_;     // 184320
constexpr int HID_  = 768;
constexpr int PHID_ = 1024;

__device__ __forceinline__ float gelu_exact(float x) {
    return 0.5f * x * (1.0f + erff(x * 0.70710678118654752440f));
}

// ---------------- tiny transpose: stem_w [192][768] -> Wt [768][192] ----------------
__global__ __launch_bounds__(256) void transpose_w_k(const float* __restrict__ w,
                                                     float* __restrict__ wt) {
    int gid = blockIdx.x * 256 + threadIdx.x;      // 147456 total
    int k = gid / 192, oc = gid % 192;
    wt[gid] = w[oc * 768 + k];                     // writes coalesced
}

// ---------------- stem: patch-embed GEMM with gathered A ----------------
// out nf[(b*576+n)*192 + oc] = sum_k patch*W + stem_b[oc] + pos[oc*576+n]
__global__ __launch_bounds__(256) void stem_gemm_k(
    const float* __restrict__ x, const float* __restrict__ Wt,
    const float* __restrict__ sb, const float* __restrict__ pos,
    float* __restrict__ nf)
{
    __shared__ float As[64][68];
    __shared__ float Ws[64][68];
    const int tid = threadIdx.x;
    const int tr = tid >> 4, tc = tid & 15;
    const int mb = blockIdx.x;          // 0..575 patch-row blocks (64 patches)
    const int nb = blockIdx.y;          // 0..2 oc blocks
    const int b  = mb / 9;
    const int n0 = (mb % 9) * 64;       // node offset within image

    float4 acc[4];
    acc[0] = acc[1] = acc[2] = acc[3] = float4{0.f, 0.f, 0.f, 0.f};

    for (int kc = 0; kc < 768; kc += 64) {
        #pragma unroll
        for (int i = 0; i < 4; ++i) {
            int q = i * 256 + tid;
            int m = q >> 4, kq = q & 15;
            int k = kc + kq * 4;
            int ci = k >> 8, rem = k & 255, dy = rem >> 4, dx = rem & 15;
            int n = n0 + m, py = n / 24, px = n % 24;
            const float* src = &x[(((size_t)(b * 3 + ci) * 384) + py * 16 + dy) * 384
                                  + px * 16 + dx];
            *(float4*)&As[m][kq * 4] = *(const float4*)src;
            *(float4*)&Ws[m][kq * 4] =
                *(const float4*)&Wt[(size_t)(kc + m) * 192 + nb * 64 + kq * 4];
        }
        __syncthreads();
        #pragma unroll
        for (int k4 = 0; k4 < 64; k4 += 4) {
            float4 a4[4], b4[4];
            #pragma unroll
            for (int i = 0; i < 4; ++i) a4[i] = *(const float4*)&As[tr * 4 + i][k4];
            #pragma unroll
            for (int kk = 0; kk < 4; ++kk) b4[kk] = *(const float4*)&Ws[k4 + kk][tc * 4];
            #pragma unroll
            for (int i = 0; i < 4; ++i) {
                const float av[4] = {a4[i].x, a4[i].y, a4[i].z, a4[i].w};
                #pragma unroll
                for (int kk = 0; kk < 4; ++kk) {
                    acc[i].x += av[kk] * b4[kk].x;
                    acc[i].y += av[kk] * b4[kk].y;
                    acc[i].z += av[kk] * b4[kk].z;
                    acc[i].w += av[kk] * b4[kk].w;
                }
            }
        }
        __syncthreads();
    }

    #pragma unroll
    for (int i = 0; i < 4; ++i) {
        int n = n0 + tr * 4 + i;
        int row = b * 576 + n;
        int oc0 = nb * 64 + tc * 4;
        float v[4] = {acc[i].x, acc[i].y, acc[i].z, acc[i].w};
        #pragma unroll
        for (int j = 0; j < 4; ++j) {
            int oc = oc0 + j;
            v[j] = v[j] + sb[oc] + pos[oc * 576 + n];
        }
        *(float4*)&nf[(size_t)row * 192 + oc0] = float4{v[0], v[1], v[2], v[3]};
    }
}

// ---------------- sq norms per node ----------------
__global__ __launch_bounds__(256) void sq_k(const float* __restrict__ nf,
                                            float* __restrict__ sq) {
    int wid = threadIdx.x >> 6, lane = threadIdx.x & 63;
    int n = blockIdx.x * 4 + wid;
    const float* row = nf + (size_t)n * 192;
    float s = 0.f;
    #pragma unroll
    for (int c = 0; c < 3; ++c) { float v = row[lane + c * 64]; s += v * v; }
    #pragma unroll
    for (int off = 32; off; off >>= 1) s += __shfl_down(s, off);
    if (lane == 0) sq[n] = s;
}

// ---------------- transpose nf per image: [b][n][c] -> [b][c][n] ----------------
__global__ void transpose_nf_k(const float* __restrict__ nf, float* __restrict__ nfT) {
    __shared__ float tile[32][33];
    int b = blockIdx.z;
    int n0 = blockIdx.x * 32, c0 = blockIdx.y * 32;
    int tx = threadIdx.x, ty = threadIdx.y;   // 32 x 8
    #pragma unroll
    for (int r = 0; r < 4; ++r) {
        int i = ty * 4 + r;
        tile[i][tx] = nf[((size_t)b * 576 + n0 + i) * 192 + c0 + tx];
    }
    __syncthreads();
    #pragma unroll
    for (int r = 0; r < 4; ++r) {
        int i = ty * 4 + r;
        nfT[((size_t)b * 192 + c0 + i) * 576 + n0 + tx] = tile[tx][i];
    }
}

// ---------------- kNN: Gram tile + running top-5 (stable ties like lax.top_k) ----------------
__global__ __launch_bounds__(256) void knn_topk_k(
    const float* __restrict__ nf, const float* __restrict__ nfT,
    const float* __restrict__ sqn, int* __restrict__ idxOut)
{
    __shared__ float As[64][68];
    __shared__ float Cs[64][68];
    __shared__ float d2s[64][68];
    const int tid = threadIdx.x;
    const int tr = tid >> 4, tc = tid & 15;
    const int b = blockIdx.x;
    const int row0 = blockIdx.y * 64;

    float tv[5];
    int ti[5];
    #pragma unroll
    for (int p = 0; p < 5; ++p) { tv[p] = 3.4e38f; ti[p] = 0; }

    for (int cc = 0; cc < 9; ++cc) {
        float4 acc[4];
        acc[0] = acc[1] = acc[2] = acc[3] = float4{0.f, 0.f, 0.f, 0.f};
        for (int kc = 0; kc < 192; kc += 64) {
            #pragma unroll
            for (int i = 0; i < 4; ++i) {
                int q = i * 256 + tid;
                int m = q >> 4, kq = q & 15;
                *(float4*)&As[m][kq * 4] =
                    *(const float4*)&nf[((size_t)(b * 576 + row0 + m)) * 192 + kc + kq * 4];
                *(float4*)&Cs[m][kq * 4] =
                    *(const float4*)&nfT[((size_t)(b * 192 + kc + m)) * 576 + cc * 64 + kq * 4];
            }
            __syncthreads();
            #pragma unroll
            for (int k4 = 0; k4 < 64; k4 += 4) {
                float4 a4[4], b4[4];
                #pragma unroll
                for (int i = 0; i < 4; ++i) a4[i] = *(const float4*)&As[tr * 4 + i][k4];
                #pragma unroll
                for (int kk = 0; kk < 4; ++kk) b4[kk] = *(const float4*)&Cs[k4 + kk][tc * 4];
                #pragma unroll
                for (int i = 0; i < 4; ++i) {
                    const float av[4] = {a4[i].x, a4[i].y, a4[i].z, a4[i].w};
                    #pragma unroll
                    for (int kk = 0; kk < 4; ++kk) {
                        acc[i].x += av[kk] * b4[kk].x;
                        acc[i].y += av[kk] * b4[kk].y;
                        acc[i].z += av[kk] * b4[kk].z;
                        acc[i].w += av[kk] * b4[kk].w;
                    }
                }
            }
            __syncthreads();
        }
        // d2 = sq_r + sq_c - 2*dot (+1e9 on diagonal), same formula as reference
        #pragma unroll
        for (int i = 0; i < 4; ++i) {
            int rl = tr * 4 + i, rg = row0 + rl;
            float sr = sqn[b * 576 + rg];
            float vv[4] = {acc[i].x, acc[i].y, acc[i].z, acc[i].w};
            #pragma unroll
            for (int j = 0; j < 4; ++j) {
                int cl = tc * 4 + j, cg = cc * 64 + cl;
                float d = sr + sqn[b * 576 + cg] - 2.f * vv[j];
                if (cg == rg) d += 1e9f;
                d2s[rl][cl] = d;
            }
        }
        __syncthreads();
        if (tid < 64) {
            for (int j = 0; j < 64; ++j) {
                float cv = d2s[tid][j];
                if (cv < tv[4]) {
                    int cidx = cc * 64 + j;
                    // stable sorted insert: strict '<' keeps earlier index on ties
                    #pragma unroll
                    for (int p = 0; p < 5; ++p) {
                        bool less = cv < tv[p];
                        float nv = less ? tv[p] : cv;
                        int ni   = less ? ti[p] : cidx;
                        tv[p] = less ? cv : tv[p];
                        ti[p] = less ? cidx : ti[p];
                        cv = nv; cidx = ni;
                    }
                }
            }
        }
        __syncthreads();
    }
    if (tid < 64) {
        int rg = b * 576 + row0 + tid;
        #pragma unroll
        for (int p = 0; p < 5; ++p) idxOut[rg * 5 + p] = b * 576 + ti[p];
    }
}

// ---------------- generic 64x64-tile f32 GEMM, templated epilogue ----------------
// EPI: 0 none, 1 +bias, 2 relu(x+bias), 3 gelu((x+bias)*g+be), 4 res + (x+bias)*g+be
template <int EPI>
__global__ __launch_bounds__(256) void gemm_rm_k(
    const float* __restrict__ A, const float* __restrict__ W, float* __restrict__ out,
    int M, int N, int K,
    const float* __restrict__ bias, const float* __restrict__ gsc,
    const float* __restrict__ gsh, const float* __restrict__ res)
{
    __shared__ float As[64][68];
    __shared__ float Ws[64][68];
    const int tid = threadIdx.x;
    const int tr = tid >> 4, tc = tid & 15;
    const int mBase = blockIdx.x * 64, nBase = blockIdx.y * 64;

    float4 acc[4];
    acc[0] = acc[1] = acc[2] = acc[3] = float4{0.f, 0.f, 0.f, 0.f};

    for (int kc = 0; kc < K; kc += 64) {
        #pragma unroll
        for (int i = 0; i < 4; ++i) {
            int q = i * 256 + tid;
            int m = q >> 4, kq = q & 15;
            *(float4*)&As[m][kq * 4] =
                *(const float4*)&A[(size_t)(mBase + m) * K + kc + kq * 4];
            *(float4*)&Ws[m][kq * 4] =
                *(const float4*)&W[(size_t)(kc + m) * N + nBase + kq * 4];
        }
        __syncthreads();
        #pragma unroll
        for (int k4 = 0; k4 < 64; k4 += 4) {
            float4 a4[4], b4[4];
            #pragma unroll
            for (int i = 0; i < 4; ++i) a4[i] = *(const float4*)&As[tr * 4 + i][k4];
            #pragma unroll
            for (int kk = 0; kk < 4; ++kk) b4[kk] = *(const float4*)&Ws[k4 + kk][tc * 4];
            #pragma unroll
            for (int i = 0; i < 4; ++i) {
                const float av[4] = {a4[i].x, a4[i].y, a4[i].z, a4[i].w};
                #pragma unroll
                for (int kk = 0; kk < 4; ++kk) {
                    acc[i].x += av[kk] * b4[kk].x;
                    acc[i].y += av[kk] * b4[kk].y;
                    acc[i].z += av[kk] * b4[kk].z;
                    acc[i].w += av[kk] * b4[kk].w;
                }
            }
        }
        __syncthreads();
    }

    #pragma unroll
    for (int i = 0; i < 4; ++i) {
        int row = mBase + tr * 4 + i;
        int n0 = nBase + tc * 4;
        float v[4] = {acc[i].x, acc[i].y, acc[i].z, acc[i].w};
        #pragma unroll
        for (int j = 0; j < 4; ++j) {
            int n = n0 + j;
            float xv = v[j];
            if (EPI == 1) xv += bias[n];
            if (EPI == 2) { xv += bias[n]; xv = fmaxf(xv, 0.f); }
            if (EPI == 3) { xv = (xv + bias[n]) * gsc[n] + gsh[n]; xv = gelu_exact(xv); }
            if (EPI == 4) {
                xv = res[(size_t)row * N + n] + (xv + bias[n]) * gsc[n] + gsh[n];
            }
            v[j] = xv;
        }
        *(float4*)&out[(size_t)row * N + n0] = float4{v[0], v[1], v[2], v[3]};
    }
}

// ---------------- edge attention: sigmoid( relu(hA[src]+hB[dst]) . w2 + b2 ) ----------------
__global__ __launch_bounds__(256) void edge_att_k(
    const float* __restrict__ hA, const float* __restrict__ hB,
    const int* __restrict__ idx, const float* __restrict__ w2,
    const float* __restrict__ b2, float* __restrict__ att)
{
    int wid = threadIdx.x >> 6, lane = threadIdx.x & 63;
    int e = blockIdx.x * 4 + wid;
    int dst = e / K_;
    int src = idx[e];
    float s = 0.f;
    #pragma unroll
    for (int c0 = 0; c0 < 3; ++c0) {
        int c = lane + c0 * 64;
        float v = hA[(size_t)src * 192 + c] + hB[(size_t)dst * 192 + c];
        v = fmaxf(v, 0.f);
        s += v * w2[c];
    }
    #pragma unroll
    for (int off = 32; off; off >>= 1) s += __shfl_down(s, off);
    if (lane == 0) att[e] = 1.f / (1.f + expf(-(s + b2[0])));
}

// ---------------- message: s[n][c] = h[n][c] + sum_p att*h[src_p][c] ----------------
__global__ __launch_bounds__(256) void msg_k(
    const float* __restrict__ h, const float* __restrict__ att,
    const int* __restrict__ idx, float* __restrict__ s)
{
    int g = blockIdx.x * 256 + threadIdx.x;  // < BN*192
    int n = g / 192, c = g % 192;
    float acc = h[g];
    #pragma unroll
    for (int p = 0; p < K_; ++p) {
        int sp = idx[n * K_ + p];
        acc += att[n * K_ + p] * h[(size_t)sp * 192 + c];
    }
    s[g] = acc;
}

// ---------------- global average pool over nodes ----------------
__global__ void pool_k(const float* __restrict__ t, float* __restrict__ g) {
    int b = blockIdx.x, c = threadIdx.x;   // 192 threads
    float s = 0.f;
    for (int n = 0; n < 576; ++n) s += t[((size_t)b * 576 + n) * 192 + c];
    g[b * 192 + c] = s * (1.f / 576.f);
}

// ---------------- head reduce: pred[b] = p[b,:] . w2 + b2 ----------------
__global__ __launch_bounds__(256) void head2_k(
    const float* __restrict__ p, const float* __restrict__ w2,
    const float* __restrict__ b2, float* __restrict__ out)
{
    int b = blockIdx.x;
    float s = 0.f;
    for (int j = threadIdx.x; j < 1024; j += 256) s += p[(size_t)b * 1024 + j] * w2[j];
    #pragma unroll
    for (int off = 32; off; off >>= 1) s += __shfl_down(s, off);
    __shared__ float ls[4];
    int wid = threadIdx.x >> 6, lane = threadIdx.x & 63;
    if (lane == 0) ls[wid] = s;
    __syncthreads();
    if (threadIdx.x == 0) out[b] = ls[0] + ls[1] + ls[2] + ls[3] + b2[0];
}

// ---------------- launch ----------------
extern "C" void kernel_launch(void* const* d_in, const int* in_sizes, int n_in,
                              void* d_out, int out_size, void* d_ws, size_t ws_size,
                              hipStream_t stream) {
    const float* x        = (const float*)d_in[0];
    const float* stem_w   = (const float*)d_in[1];
    const float* stem_b   = (const float*)d_in[2];
    const float* pos      = (const float*)d_in[3];
    const float* att_w1   = (const float*)d_in[4];
    const float* att_b1   = (const float*)d_in[5];
    const float* att_w2   = (const float*)d_in[6];
    const float* att_b2   = (const float*)d_in[7];
    const float* gnn_w1   = (const float*)d_in[8];
    const float* gnn_b1   = (const float*)d_in[9];
    const float* gnn_w2   = (const float*)d_in[10];
    const float* gnn_b2   = (const float*)d_in[11];
    const float* ffn_w1   = (const float*)d_in[12];
    const float* ffn_b1   = (const float*)d_in[13];
    const float* ffn_g1   = (const float*)d_in[14];
    const float* ffn_be1  = (const float*)d_in[15];
    const float* ffn_w2   = (const float*)d_in[16];
    const float* ffn_b2   = (const float*)d_in[17];
    const float* ffn_g2   = (const float*)d_in[18];
    const float* ffn_be2  = (const float*)d_in[19];
    const float* pred_w1  = (const float*)d_in[20];
    const float* pred_b1  = (const float*)d_in[21];
    const float* pred_g   = (const float*)d_in[22];
    const float* pred_be  = (const float*)d_in[23];
    const float* pred_w2  = (const float*)d_in[24];
    const float* pred_b2  = (const float*)d_in[25];

    float* ws = (float*)d_ws;
    const size_t RSZ = (size_t)BN_ * C_;          // 7,077,888 floats
    float* R0 = ws;               // nf -> h -> h3
    float* R1 = R0 + RSZ;         // hA -> s -> t_out
    float* R2 = R1 + RSZ;         // hB -> h2
    float* R3 = R2 + RSZ;         // Wt / nfT / u-chunk
    float* sqb = R3 + RSZ;        // BN
    int*   idxb = (int*)(sqb + BN_);              // E ints
    float* gb = (float*)(idxb + E_);              // 64*192
    float* pb = gb + 64 * C_;                     // 64*1024

    float* att  = (float*)d_out;                  // E
    float* pred = att + E_;                       // 64

    float* Wt = R3;  // alias: used only by stem before nfT is written

    // 1. stem
    transpose_w_k<<<576, 256, 0, stream>>>(stem_w, Wt);
    stem_gemm_k<<<dim3(576, 3), 256, 0, stream>>>(x, Wt, stem_b, pos, R0);

    // 2. kNN graph
    sq_k<<<BN_ / 4, 256, 0, stream>>>(R0, sqb);
    transpose_nf_k<<<dim3(18, 6, 64), dim3(32, 8), 0, stream>>>(R0, R3);
    knn_topk_k<<<dim3(64, 9), 256, 0, stream>>>(R0, R3, sqb, idxb);

    // 3. edge attention (factored concat-MLP)
    gemm_rm_k<0><<<dim3(576, 3), 256, 0, stream>>>(R0, att_w1, R1,
        BN_, 192, 192, nullptr, nullptr, nullptr, nullptr);
    gemm_rm_k<1><<<dim3(576, 3), 256, 0, stream>>>(R0, att_w1 + 192 * 192, R2,
        BN_, 192, 192, att_b1, nullptr, nullptr, nullptr);
    edge_att_k<<<E_ / 4, 256, 0, stream>>>(R1, R2, idxb, att_w2, att_b2, att);

    // 4. GNN layer 1
    msg_k<<<BN_ * C_ / 256, 256, 0, stream>>>(R0, att, idxb, R1);
    gemm_rm_k<2><<<dim3(576, 3), 256, 0, stream>>>(R1, gnn_w1, R2,
        BN_, 192, 192, gnn_b1, nullptr, nullptr, nullptr);
    // 5. GNN layer 2
    msg_k<<<BN_ * C_ / 256, 256, 0, stream>>>(R2, att, idxb, R1);
    gemm_rm_k<2><<<dim3(576, 3), 256, 0, stream>>>(R1, gnn_w2, R0,
        BN_, 192, 192, gnn_b2, nullptr, nullptr, nullptr);

    // 6. FFN in 4 node-chunks (u buffer = R3, 9216x768)
    for (int ch = 0; ch < 4; ++ch) {
        const float* Ain = R0 + (size_t)ch * 9216 * 192;
        float* Tout = R1 + (size_t)ch * 9216 * 192;
        gemm_rm_k<3><<<dim3(144, 12), 256, 0, stream>>>(Ain, ffn_w1, R3,
            9216, 768, 192, ffn_b1, ffn_g1, ffn_be1, nullptr);
        gemm_rm_k<4><<<dim3(144, 3), 256, 0, stream>>>(R3, ffn_w2, Tout,
            9216, 192, 768, ffn_b2, ffn_g2, ffn_be2, Ain);
    }

    // 7. pool + head
    pool_k<<<64, 192, 0, stream>>>(R1, gb);
    gemm_rm_k<3><<<dim3(1, 16), 256, 0, stream>>>(gb, pred_w1, pb,
        64, 1024, 192, pred_b1, pred_g, pred_be, nullptr);
    head2_k<<<64, 256, 0, stream>>>(pb, pred_w2, pred_b2, pred);
}

// Round 3
// 1292.086 us; speedup vs baseline: 1.0030x; 1.0030x over previous
//
#include <hip/hip_runtime.h>
#include <math.h>

// ---------------- problem constants ----------------
constexpr int B_    = 64;
constexpr int C_    = 192;
constexpr int N_    = 576;    // nodes per image (24x24)
constexpr int BN_   = B_ * N_;      // 36864
constexpr int K_    = 5;
constexpr int E_    = BN_ * K_;     // 184320

__device__ __forceinline__ float gelu_exact(float x) {
    return 0.5f * x * (1.0f + erff(x * 0.70710678118654752440f));
}

// ---------------- tiny transpose: stem_w [192][768] -> Wt [768][192] ----------------
__global__ __launch_bounds__(256) void transpose_w_k(const float* __restrict__ w,
                                                     float* __restrict__ wt) {
    int gid = blockIdx.x * 256 + threadIdx.x;      // 147456 total
    int k = gid / 192, oc = gid % 192;
    wt[gid] = w[oc * 768 + k];                     // writes coalesced
}

// ---------------- stem: patch-embed GEMM with gathered A (UNCHANGED from R1: feeds kNN bits) ----------------
__global__ __launch_bounds__(256) void stem_gemm_k(
    const float* __restrict__ x, const float* __restrict__ Wt,
    const float* __restrict__ sb, const float* __restrict__ pos,
    float* __restrict__ nf)
{
    __shared__ float As[64][68];
    __shared__ float Ws[64][68];
    const int tid = threadIdx.x;
    const int tr = tid >> 4, tc = tid & 15;
    const int mb = blockIdx.x;          // 0..575 patch-row blocks (64 patches)
    const int nb = blockIdx.y;          // 0..2 oc blocks
    const int b  = mb / 9;
    const int n0 = (mb % 9) * 64;       // node offset within image

    float4 acc[4];
    acc[0] = acc[1] = acc[2] = acc[3] = float4{0.f, 0.f, 0.f, 0.f};

    for (int kc = 0; kc < 768; kc += 64) {
        #pragma unroll
        for (int i = 0; i < 4; ++i) {
            int q = i * 256 + tid;
            int m = q >> 4, kq = q & 15;
            int k = kc + kq * 4;
            int ci = k >> 8, rem = k & 255, dy = rem >> 4, dx = rem & 15;
            int n = n0 + m, py = n / 24, px = n % 24;
            const float* src = &x[(((size_t)(b * 3 + ci) * 384) + py * 16 + dy) * 384
                                  + px * 16 + dx];
            *(float4*)&As[m][kq * 4] = *(const float4*)src;
            *(float4*)&Ws[m][kq * 4] =
                *(const float4*)&Wt[(size_t)(kc + m) * 192 + nb * 64 + kq * 4];
        }
        __syncthreads();
        #pragma unroll
        for (int k4 = 0; k4 < 64; k4 += 4) {
            float4 a4[4], b4[4];
            #pragma unroll
            for (int i = 0; i < 4; ++i) a4[i] = *(const float4*)&As[tr * 4 + i][k4];
            #pragma unroll
            for (int kk = 0; kk < 4; ++kk) b4[kk] = *(const float4*)&Ws[k4 + kk][tc * 4];
            #pragma unroll
            for (int i = 0; i < 4; ++i) {
                const float av[4] = {a4[i].x, a4[i].y, a4[i].z, a4[i].w};
                #pragma unroll
                for (int kk = 0; kk < 4; ++kk) {
                    acc[i].x += av[kk] * b4[kk].x;
                    acc[i].y += av[kk] * b4[kk].y;
                    acc[i].z += av[kk] * b4[kk].z;
                    acc[i].w += av[kk] * b4[kk].w;
                }
            }
        }
        __syncthreads();
    }

    #pragma unroll
    for (int i = 0; i < 4; ++i) {
        int n = n0 + tr * 4 + i;
        int row = b * 576 + n;
        int oc0 = nb * 64 + tc * 4;
        float v[4] = {acc[i].x, acc[i].y, acc[i].z, acc[i].w};
        #pragma unroll
        for (int j = 0; j < 4; ++j) {
            int oc = oc0 + j;
            v[j] = v[j] + sb[oc] + pos[oc * 576 + n];
        }
        *(float4*)&nf[(size_t)row * 192 + oc0] = float4{v[0], v[1], v[2], v[3]};
    }
}

// ---------------- sq norms per node (UNCHANGED from R1) ----------------
__global__ __launch_bounds__(256) void sq_k(const float* __restrict__ nf,
                                            float* __restrict__ sq) {
    int wid = threadIdx.x >> 6, lane = threadIdx.x & 63;
    int n = blockIdx.x * 4 + wid;
    const float* row = nf + (size_t)n * 192;
    float s = 0.f;
    #pragma unroll
    for (int c = 0; c < 3; ++c) { float v = row[lane + c * 64]; s += v * v; }
    #pragma unroll
    for (int off = 32; off; off >>= 1) s += __shfl_down(s, off);
    if (lane == 0) sq[n] = s;
}

// ---------------- transpose nf per image (UNCHANGED from R1) ----------------
__global__ void transpose_nf_k(const float* __restrict__ nf, float* __restrict__ nfT) {
    __shared__ float tile[32][33];
    int b = blockIdx.z;
    int n0 = blockIdx.x * 32, c0 = blockIdx.y * 32;
    int tx = threadIdx.x, ty = threadIdx.y;   // 32 x 8
    #pragma unroll
    for (int r = 0; r < 4; ++r) {
        int i = ty * 4 + r;
        tile[i][tx] = nf[((size_t)b * 576 + n0 + i) * 192 + c0 + tx];
    }
    __syncthreads();
    #pragma unroll
    for (int r = 0; r < 4; ++r) {
        int i = ty * 4 + r;
        nfT[((size_t)b * 192 + c0 + i) * 576 + n0 + tx] = tile[tx][i];
    }
}

// ---------------- kNN: Gram tile + running top-5 (UNCHANGED from R1 — bit-sensitive) ----------------
__global__ __launch_bounds__(256) void knn_topk_k(
    const float* __restrict__ nf, const float* __restrict__ nfT,
    const float* __restrict__ sqn, int* __restrict__ idxOut)
{
    __shared__ float As[64][68];
    __shared__ float Cs[64][68];
    __shared__ float d2s[64][68];
    const int tid = threadIdx.x;
    const int tr = tid >> 4, tc = tid & 15;
    const int b = blockIdx.x;
    const int row0 = blockIdx.y * 64;

    float tv[5];
    int ti[5];
    #pragma unroll
    for (int p = 0; p < 5; ++p) { tv[p] = 3.4e38f; ti[p] = 0; }

    for (int cc = 0; cc < 9; ++cc) {
        float4 acc[4];
        acc[0] = acc[1] = acc[2] = acc[3] = float4{0.f, 0.f, 0.f, 0.f};
        for (int kc = 0; kc < 192; kc += 64) {
            #pragma unroll
            for (int i = 0; i < 4; ++i) {
                int q = i * 256 + tid;
                int m = q >> 4, kq = q & 15;
                *(float4*)&As[m][kq * 4] =
                    *(const float4*)&nf[((size_t)(b * 576 + row0 + m)) * 192 + kc + kq * 4];
                *(float4*)&Cs[m][kq * 4] =
                    *(const float4*)&nfT[((size_t)(b * 192 + kc + m)) * 576 + cc * 64 + kq * 4];
            }
            __syncthreads();
            #pragma unroll
            for (int k4 = 0; k4 < 64; k4 += 4) {
                float4 a4[4], b4[4];
                #pragma unroll
                for (int i = 0; i < 4; ++i) a4[i] = *(const float4*)&As[tr * 4 + i][k4];
                #pragma unroll
                for (int kk = 0; kk < 4; ++kk) b4[kk] = *(const float4*)&Cs[k4 + kk][tc * 4];
                #pragma unroll
                for (int i = 0; i < 4; ++i) {
                    const float av[4] = {a4[i].x, a4[i].y, a4[i].z, a4[i].w};
                    #pragma unroll
                    for (int kk = 0; kk < 4; ++kk) {
                        acc[i].x += av[kk] * b4[kk].x;
                        acc[i].y += av[kk] * b4[kk].y;
                        acc[i].z += av[kk] * b4[kk].z;
                        acc[i].w += av[kk] * b4[kk].w;
                    }
                }
            }
            __syncthreads();
        }
        // d2 = sq_r + sq_c - 2*dot (+1e9 on diagonal), same formula as reference
        #pragma unroll
        for (int i = 0; i < 4; ++i) {
            int rl = tr * 4 + i, rg = row0 + rl;
            float sr = sqn[b * 576 + rg];
            float vv[4] = {acc[i].x, acc[i].y, acc[i].z, acc[i].w};
            #pragma unroll
            for (int j = 0; j < 4; ++j) {
                int cl = tc * 4 + j, cg = cc * 64 + cl;
                float d = sr + sqn[b * 576 + cg] - 2.f * vv[j];
                if (cg == rg) d += 1e9f;
                d2s[rl][cl] = d;
            }
        }
        __syncthreads();
        if (tid < 64) {
            for (int j = 0; j < 64; ++j) {
                float cv = d2s[tid][j];
                if (cv < tv[4]) {
                    int cidx = cc * 64 + j;
                    // stable sorted insert: strict '<' keeps earlier index on ties
                    #pragma unroll
                    for (int p = 0; p < 5; ++p) {
                        bool less = cv < tv[p];
                        float nv = less ? tv[p] : cv;
                        int ni   = less ? ti[p] : cidx;
                        tv[p] = less ? cv : tv[p];
                        ti[p] = less ? cidx : ti[p];
                        cv = nv; cidx = ni;
                    }
                }
            }
        }
        __syncthreads();
    }
    if (tid < 64) {
        int rg = b * 576 + row0 + tid;
        #pragma unroll
        for (int p = 0; p < 5; ++p) idxOut[rg * 5 + p] = b * 576 + ti[p];
    }
}

// ---------------- generic 64x64-tile f32 GEMM (kept for small shapes) ----------------
// EPI: 0 none, 1 +bias, 2 relu(x+bias), 3 gelu((x+bias)*g+be), 4 res + (x+bias)*g+be
template <int EPI>
__global__ __launch_bounds__(256) void gemm_rm_k(
    const float* __restrict__ A, const float* __restrict__ W, float* __restrict__ out,
    int M, int N, int K,
    const float* __restrict__ bias, const float* __restrict__ gsc,
    const float* __restrict__ gsh, const float* __restrict__ res)
{
    __shared__ float As[64][68];
    __shared__ float Ws[64][68];
    const int tid = threadIdx.x;
    const int tr = tid >> 4, tc = tid & 15;
    const int mBase = blockIdx.x * 64, nBase = blockIdx.y * 64;

    float4 acc[4];
    acc[0] = acc[1] = acc[2] = acc[3] = float4{0.f, 0.f, 0.f, 0.f};

    for (int kc = 0; kc < K; kc += 64) {
        #pragma unroll
        for (int i = 0; i < 4; ++i) {
            int q = i * 256 + tid;
            int m = q >> 4, kq = q & 15;
            *(float4*)&As[m][kq * 4] =
                *(const float4*)&A[(size_t)(mBase + m) * K + kc + kq * 4];
            *(float4*)&Ws[m][kq * 4] =
                *(const float4*)&W[(size_t)(kc + m) * N + nBase + kq * 4];
        }
        __syncthreads();
        #pragma unroll
        for (int k4 = 0; k4 < 64; k4 += 4) {
            float4 a4[4], b4[4];
            #pragma unroll
            for (int i = 0; i < 4; ++i) a4[i] = *(const float4*)&As[tr * 4 + i][k4];
            #pragma unroll
            for (int kk = 0; kk < 4; ++kk) b4[kk] = *(const float4*)&Ws[k4 + kk][tc * 4];
            #pragma unroll
            for (int i = 0; i < 4; ++i) {
                const float av[4] = {a4[i].x, a4[i].y, a4[i].z, a4[i].w};
                #pragma unroll
                for (int kk = 0; kk < 4; ++kk) {
                    acc[i].x += av[kk] * b4[kk].x;
                    acc[i].y += av[kk] * b4[kk].y;
                    acc[i].z += av[kk] * b4[kk].z;
                    acc[i].w += av[kk] * b4[kk].w;
                }
            }
        }
        __syncthreads();
    }

    #pragma unroll
    for (int i = 0; i < 4; ++i) {
        int row = mBase + tr * 4 + i;
        int n0 = nBase + tc * 4;
        float v[4] = {acc[i].x, acc[i].y, acc[i].z, acc[i].w};
        #pragma unroll
        for (int j = 0; j < 4; ++j) {
            int n = n0 + j;
            float xv = v[j];
            if (EPI == 1) xv += bias[n];
            if (EPI == 2) { xv += bias[n]; xv = fmaxf(xv, 0.f); }
            if (EPI == 3) { xv = (xv + bias[n]) * gsc[n] + gsh[n]; xv = gelu_exact(xv); }
            if (EPI == 4) {
                xv = res[(size_t)row * N + n] + (xv + bias[n]) * gsc[n] + gsh[n];
            }
            v[j] = xv;
        }
        *(float4*)&out[(size_t)row * N + n0] = float4{v[0], v[1], v[2], v[3]};
    }
}

// ---------------- 128x64-tile f32 GEMM, 8x4 micro — same ascending-k FMA chain ----------------
template <int EPI>
__global__ __launch_bounds__(256) void gemm128_k(
    const float* __restrict__ A, const float* __restrict__ W, float* __restrict__ out,
    int M, int N, int K,
    const float* __restrict__ bias, const float* __restrict__ gsc,
    const float* __restrict__ gsh, const float* __restrict__ res)
{
    __shared__ float As[128][68];
    __shared__ float Ws[64][68];
    const int tid = threadIdx.x;
    const int tr = tid >> 4, tc = tid & 15;
    const int mBase = blockIdx.x * 128, nBase = blockIdx.y * 64;

    float4 acc[8];
    #pragma unroll
    for (int i = 0; i < 8; ++i) acc[i] = float4{0.f, 0.f, 0.f, 0.f};

    for (int kc = 0; kc < K; kc += 64) {
        #pragma unroll
        for (int i = 0; i < 8; ++i) {
            int q = i * 256 + tid;
            int m = q >> 4, kq = q & 15;       // m < 128
            *(float4*)&As[m][kq * 4] =
                *(const float4*)&A[(size_t)(mBase + m) * K + kc + kq * 4];
        }
        #pragma unroll
        for (int i = 0; i < 4; ++i) {
            int q = i * 256 + tid;
            int m = q >> 4, kq = q & 15;       // m < 64
            *(float4*)&Ws[m][kq * 4] =
                *(const float4*)&W[(size_t)(kc + m) * N + nBase + kq * 4];
        }
        __syncthreads();
        #pragma unroll
        for (int k4 = 0; k4 < 64; k4 += 4) {
            float4 a4[8], b4[4];
            #pragma unroll
            for (int i = 0; i < 8; ++i) a4[i] = *(const float4*)&As[tr * 8 + i][k4];
            #pragma unroll
            for (int kk = 0; kk < 4; ++kk) b4[kk] = *(const float4*)&Ws[k4 + kk][tc * 4];
            #pragma unroll
            for (int i = 0; i < 8; ++i) {
                const float av[4] = {a4[i].x, a4[i].y, a4[i].z, a4[i].w};
                #pragma unroll
                for (int kk = 0; kk < 4; ++kk) {
                    acc[i].x += av[kk] * b4[kk].x;
                    acc[i].y += av[kk] * b4[kk].y;
                    acc[i].z += av[kk] * b4[kk].z;
                    acc[i].w += av[kk] * b4[kk].w;
                }
            }
        }
        __syncthreads();
    }

    #pragma unroll
    for (int i = 0; i < 8; ++i) {
        int row = mBase + tr * 8 + i;
        int n0 = nBase + tc * 4;
        float v[4] = {acc[i].x, acc[i].y, acc[i].z, acc[i].w};
        #pragma unroll
        for (int j = 0; j < 4; ++j) {
            int n = n0 + j;
            float xv = v[j];
            if (EPI == 1) xv += bias[n];
            if (EPI == 2) { xv += bias[n]; xv = fmaxf(xv, 0.f); }
            if (EPI == 3) { xv = (xv + bias[n]) * gsc[n] + gsh[n]; xv = gelu_exact(xv); }
            if (EPI == 4) {
                xv = res[(size_t)row * N + n] + (xv + bias[n]) * gsc[n] + gsh[n];
            }
            v[j] = xv;
        }
        *(float4*)&out[(size_t)row * N + n0] = float4{v[0], v[1], v[2], v[3]};
    }
}

// ---------------- edge attention: sigmoid( relu(hA[src]+hB[dst]) . w2 + b2 ) ----------------
__global__ __launch_bounds__(256) void edge_att_k(
    const float* __restrict__ hA, const float* __restrict__ hB,
    const int* __restrict__ idx, const float* __restrict__ w2,
    const float* __restrict__ b2, float* __restrict__ att)
{
    int wid = threadIdx.x >> 6, lane = threadIdx.x & 63;
    int e = blockIdx.x * 4 + wid;
    int dst = e / K_;
    int src = idx[e];
    float s = 0.f;
    #pragma unroll
    for (int c0 = 0; c0 < 3; ++c0) {
        int c = lane + c0 * 64;
        float v = hA[(size_t)src * 192 + c] + hB[(size_t)dst * 192 + c];
        v = fmaxf(v, 0.f);
        s += v * w2[c];
    }
    #pragma unroll
    for (int off = 32; off; off >>= 1) s += __shfl_down(s, off);
    if (lane == 0) att[e] = 1.f / (1.f + expf(-(s + b2[0])));
}

// ---------------- message: s[n][c] = h[n][c] + sum_p att*h[src_p][c] ----------------
__global__ __launch_bounds__(256) void msg_k(
    const float* __restrict__ h, const float* __restrict__ att,
    const int* __restrict__ idx, float* __restrict__ s)
{
    int g = blockIdx.x * 256 + threadIdx.x;  // < BN*192
    int n = g / 192, c = g % 192;
    float acc = h[g];
    #pragma unroll
    for (int p = 0; p < K_; ++p) {
        int sp = idx[n * K_ + p];
        acc += att[n * K_ + p] * h[(size_t)sp * 192 + c];
    }
    s[g] = acc;
}

// ---------------- global average pool over nodes ----------------
__global__ void pool_k(const float* __restrict__ t, float* __restrict__ g) {
    int b = blockIdx.x, c = threadIdx.x;   // 192 threads
    float s = 0.f;
    for (int n = 0; n < 576; ++n) s += t[((size_t)b * 576 + n) * 192 + c];
    g[b * 192 + c] = s * (1.f / 576.f);
}

// ---------------- head reduce: pred[b] = p[b,:] . w2 + b2 ----------------
__global__ __launch_bounds__(256) void head2_k(
    const float* __restrict__ p, const float* __restrict__ w2,
    const float* __restrict__ b2, float* __restrict__ out)
{
    int b = blockIdx.x;
    float s = 0.f;
    for (int j = threadIdx.x; j < 1024; j += 256) s += p[(size_t)b * 1024 + j] * w2[j];
    #pragma unroll
    for (int off = 32; off; off >>= 1) s += __shfl_down(s, off);
    __shared__ float ls[4];
    int wid = threadIdx.x >> 6, lane = threadIdx.x & 63;
    if (lane == 0) ls[wid] = s;
    __syncthreads();
    if (threadIdx.x == 0) out[b] = ls[0] + ls[1] + ls[2] + ls[3] + b2[0];
}

// ---------------- launch ----------------
extern "C" void kernel_launch(void* const* d_in, const int* in_sizes, int n_in,
                              void* d_out, int out_size, void* d_ws, size_t ws_size,
                              hipStream_t stream) {
    const float* x        = (const float*)d_in[0];
    const float* stem_w   = (const float*)d_in[1];
    const float* stem_b   = (const float*)d_in[2];
    const float* pos      = (const float*)d_in[3];
    const float* att_w1   = (const float*)d_in[4];
    const float* att_b1   = (const float*)d_in[5];
    const float* att_w2   = (const float*)d_in[6];
    const float* att_b2   = (const float*)d_in[7];
    const float* gnn_w1   = (const float*)d_in[8];
    const float* gnn_b1   = (const float*)d_in[9];
    const float* gnn_w2   = (const float*)d_in[10];
    const float* gnn_b2   = (const float*)d_in[11];
    const float* ffn_w1   = (const float*)d_in[12];
    const float* ffn_b1   = (const float*)d_in[13];
    const float* ffn_g1   = (const float*)d_in[14];
    const float* ffn_be1  = (const float*)d_in[15];
    const float* ffn_w2   = (const float*)d_in[16];
    const float* ffn_b2   = (const float*)d_in[17];
    const float* ffn_g2   = (const float*)d_in[18];
    const float* ffn_be2  = (const float*)d_in[19];
    const float* pred_w1  = (const float*)d_in[20];
    const float* pred_b1  = (const float*)d_in[21];
    const float* pred_g   = (const float*)d_in[22];
    const float* pred_be  = (const float*)d_in[23];
    const float* pred_w2  = (const float*)d_in[24];
    const float* pred_b2  = (const float*)d_in[25];

    float* ws = (float*)d_ws;
    const size_t RSZ = (size_t)BN_ * C_;          // 7,077,888 floats
    float* R0 = ws;               // nf -> h -> h3
    float* R1 = R0 + RSZ;         // hA -> s -> t_out
    float* R2 = R1 + RSZ;         // hB -> h2
    float* R3 = R2 + RSZ;         // Wt / nfT / u-chunk
    float* sqb = R3 + RSZ;        // BN
    int*   idxb = (int*)(sqb + BN_);              // E ints
    float* gb = (float*)(idxb + E_);              // 64*192
    float* pb = gb + 64 * C_;                     // 64*1024

    float* att  = (float*)d_out;                  // E
    float* pred = att + E_;                       // 64

    float* Wt = R3;  // alias: used only by stem before nfT is written

    // 1. stem
    transpose_w_k<<<576, 256, 0, stream>>>(stem_w, Wt);
    stem_gemm_k<<<dim3(576, 3), 256, 0, stream>>>(x, Wt, stem_b, pos, R0);

    // 2. kNN graph (R1's exact kernel — bit-sensitive path)
    sq_k<<<BN_ / 4, 256, 0, stream>>>(R0, sqb);
    transpose_nf_k<<<dim3(18, 6, 64), dim3(32, 8), 0, stream>>>(R0, R3);
    knn_topk_k<<<dim3(64, 9), 256, 0, stream>>>(R0, R3, sqb, idxb);

    // 3. edge attention (factored concat-MLP) — 128-tile, bit-identical k-chain
    gemm128_k<0><<<dim3(288, 3), 256, 0, stream>>>(R0, att_w1, R1,
        BN_, 192, 192, nullptr, nullptr, nullptr, nullptr);
    gemm128_k<1><<<dim3(288, 3), 256, 0, stream>>>(R0, att_w1 + 192 * 192, R2,
        BN_, 192, 192, att_b1, nullptr, nullptr, nullptr);
    edge_att_k<<<E_ / 4, 256, 0, stream>>>(R1, R2, idxb, att_w2, att_b2, att);

    // 4. GNN layer 1
    msg_k<<<BN_ * C_ / 256, 256, 0, stream>>>(R0, att, idxb, R1);
    gemm128_k<2><<<dim3(288, 3), 256, 0, stream>>>(R1, gnn_w1, R2,
        BN_, 192, 192, gnn_b1, nullptr, nullptr, nullptr);
    // 5. GNN layer 2
    msg_k<<<BN_ * C_ / 256, 256, 0, stream>>>(R2, att, idxb, R1);
    gemm128_k<2><<<dim3(288, 3), 256, 0, stream>>>(R1, gnn_w2, R0,
        BN_, 192, 192, gnn_b2, nullptr, nullptr, nullptr);

    // 6. FFN in 4 node-chunks (u buffer = R3, 9216x768)
    for (int ch = 0; ch < 4; ++ch) {
        const float* Ain = R0 + (size_t)ch * 9216 * 192;
        float* Tout = R1 + (size_t)ch * 9216 * 192;
        gemm128_k<3><<<dim3(72, 12), 256, 0, stream>>>(Ain, ffn_w1, R3,
            9216, 768, 192, ffn_b1, ffn_g1, ffn_be1, nullptr);
        gemm128_k<4><<<dim3(72, 3), 256, 0, stream>>>(R3, ffn_w2, Tout,
            9216, 192, 768, ffn_b2, ffn_g2, ffn_be2, Ain);
    }

    // 7. pool + head
    pool_k<<<64, 192, 0, stream>>>(R1, gb);
    gemm_rm_k<3><<<dim3(1, 16), 256, 0, stream>>>(gb, pred_w1, pb,
        64, 1024, 192, pred_b1, pred_g, pred_be, nullptr);
    head2_k<<<64, 256, 0, stream>>>(pb, pred_w2, pred_b2, pred);
}

// Round 4
// 917.644 us; speedup vs baseline: 1.4123x; 1.4080x over previous
//
#include <hip/hip_runtime.h>
#include <hip/hip_bf16.h>
#include <math.h>

// ---------------- problem constants ----------------
constexpr int B_    = 64;
constexpr int C_    = 192;
constexpr int N_    = 576;    // nodes per image (24x24)
constexpr int BN_   = B_ * N_;      // 36864
constexpr int K_    = 5;
constexpr int E_    = BN_ * K_;     // 184320

__device__ __forceinline__ float gelu_exact(float x) {
    return 0.5f * x * (1.0f + erff(x * 0.70710678118654752440f));
}

__device__ __forceinline__ float bf2f(unsigned short v) {
    return __uint_as_float(((unsigned)v) << 16);
}
__device__ __forceinline__ unsigned short f2bf(float x) {
    __hip_bfloat16 h = __float2bfloat16(x);
    return *(unsigned short*)&h;
}

// ---------------- tiny transpose: stem_w [192][768] -> Wt [768][192] ----------------
__global__ __launch_bounds__(256) void transpose_w_k(const float* __restrict__ w,
                                                     float* __restrict__ wt) {
    int gid = blockIdx.x * 256 + threadIdx.x;      // 147456 total
    int k = gid / 192, oc = gid % 192;
    wt[gid] = w[oc * 768 + k];                     // writes coalesced
}

// ---------------- stem: patch-embed GEMM with gathered A (UNCHANGED: feeds kNN bits) ----------------
__global__ __launch_bounds__(256) void stem_gemm_k(
    const float* __restrict__ x, const float* __restrict__ Wt,
    const float* __restrict__ sb, const float* __restrict__ pos,
    float* __restrict__ nf)
{
    __shared__ float As[64][68];
    __shared__ float Ws[64][68];
    const int tid = threadIdx.x;
    const int tr = tid >> 4, tc = tid & 15;
    const int mb = blockIdx.x;          // 0..575 patch-row blocks (64 patches)
    const int nb = blockIdx.y;          // 0..2 oc blocks
    const int b  = mb / 9;
    const int n0 = (mb % 9) * 64;       // node offset within image

    float4 acc[4];
    acc[0] = acc[1] = acc[2] = acc[3] = float4{0.f, 0.f, 0.f, 0.f};

    for (int kc = 0; kc < 768; kc += 64) {
        #pragma unroll
        for (int i = 0; i < 4; ++i) {
            int q = i * 256 + tid;
            int m = q >> 4, kq = q & 15;
            int k = kc + kq * 4;
            int ci = k >> 8, rem = k & 255, dy = rem >> 4, dx = rem & 15;
            int n = n0 + m, py = n / 24, px = n % 24;
            const float* src = &x[(((size_t)(b * 3 + ci) * 384) + py * 16 + dy) * 384
                                  + px * 16 + dx];
            *(float4*)&As[m][kq * 4] = *(const float4*)src;
            *(float4*)&Ws[m][kq * 4] =
                *(const float4*)&Wt[(size_t)(kc + m) * 192 + nb * 64 + kq * 4];
        }
        __syncthreads();
        #pragma unroll
        for (int k4 = 0; k4 < 64; k4 += 4) {
            float4 a4[4], b4[4];
            #pragma unroll
            for (int i = 0; i < 4; ++i) a4[i] = *(const float4*)&As[tr * 4 + i][k4];
            #pragma unroll
            for (int kk = 0; kk < 4; ++kk) b4[kk] = *(const float4*)&Ws[k4 + kk][tc * 4];
            #pragma unroll
            for (int i = 0; i < 4; ++i) {
                const float av[4] = {a4[i].x, a4[i].y, a4[i].z, a4[i].w};
                #pragma unroll
                for (int kk = 0; kk < 4; ++kk) {
                    acc[i].x += av[kk] * b4[kk].x;
                    acc[i].y += av[kk] * b4[kk].y;
                    acc[i].z += av[kk] * b4[kk].z;
                    acc[i].w += av[kk] * b4[kk].w;
                }
            }
        }
        __syncthreads();
    }

    #pragma unroll
    for (int i = 0; i < 4; ++i) {
        int n = n0 + tr * 4 + i;
        int row = b * 576 + n;
        int oc0 = nb * 64 + tc * 4;
        float v[4] = {acc[i].x, acc[i].y, acc[i].z, acc[i].w};
        #pragma unroll
        for (int j = 0; j < 4; ++j) {
            int oc = oc0 + j;
            v[j] = v[j] + sb[oc] + pos[oc * 576 + n];
        }
        *(float4*)&nf[(size_t)row * 192 + oc0] = float4{v[0], v[1], v[2], v[3]};
    }
}

// ---------------- sq norms per node (UNCHANGED) ----------------
__global__ __launch_bounds__(256) void sq_k(const float* __restrict__ nf,
                                            float* __restrict__ sq) {
    int wid = threadIdx.x >> 6, lane = threadIdx.x & 63;
    int n = blockIdx.x * 4 + wid;
    const float* row = nf + (size_t)n * 192;
    float s = 0.f;
    #pragma unroll
    for (int c = 0; c < 3; ++c) { float v = row[lane + c * 64]; s += v * v; }
    #pragma unroll
    for (int off = 32; off; off >>= 1) s += __shfl_down(s, off);
    if (lane == 0) sq[n] = s;
}

// ---------------- transpose nf per image (UNCHANGED) ----------------
__global__ void transpose_nf_k(const float* __restrict__ nf, float* __restrict__ nfT) {
    __shared__ float tile[32][33];
    int b = blockIdx.z;
    int n0 = blockIdx.x * 32, c0 = blockIdx.y * 32;
    int tx = threadIdx.x, ty = threadIdx.y;   // 32 x 8
    #pragma unroll
    for (int r = 0; r < 4; ++r) {
        int i = ty * 4 + r;
        tile[i][tx] = nf[((size_t)b * 576 + n0 + i) * 192 + c0 + tx];
    }
    __syncthreads();
    #pragma unroll
    for (int r = 0; r < 4; ++r) {
        int i = ty * 4 + r;
        nfT[((size_t)b * 192 + c0 + i) * 576 + n0 + tx] = tile[tx][i];
    }
}

// ---------------- kNN: Gram tile + running top-5 (UNCHANGED — bit-sensitive) ----------------
__global__ __launch_bounds__(256) void knn_topk_k(
    const float* __restrict__ nf, const float* __restrict__ nfT,
    const float* __restrict__ sqn, int* __restrict__ idxOut)
{
    __shared__ float As[64][68];
    __shared__ float Cs[64][68];
    __shared__ float d2s[64][68];
    const int tid = threadIdx.x;
    const int tr = tid >> 4, tc = tid & 15;
    const int b = blockIdx.x;
    const int row0 = blockIdx.y * 64;

    float tv[5];
    int ti[5];
    #pragma unroll
    for (int p = 0; p < 5; ++p) { tv[p] = 3.4e38f; ti[p] = 0; }

    for (int cc = 0; cc < 9; ++cc) {
        float4 acc[4];
        acc[0] = acc[1] = acc[2] = acc[3] = float4{0.f, 0.f, 0.f, 0.f};
        for (int kc = 0; kc < 192; kc += 64) {
            #pragma unroll
            for (int i = 0; i < 4; ++i) {
                int q = i * 256 + tid;
                int m = q >> 4, kq = q & 15;
                *(float4*)&As[m][kq * 4] =
                    *(const float4*)&nf[((size_t)(b * 576 + row0 + m)) * 192 + kc + kq * 4];
                *(float4*)&Cs[m][kq * 4] =
                    *(const float4*)&nfT[((size_t)(b * 192 + kc + m)) * 576 + cc * 64 + kq * 4];
            }
            __syncthreads();
            #pragma unroll
            for (int k4 = 0; k4 < 64; k4 += 4) {
                float4 a4[4], b4[4];
                #pragma unroll
                for (int i = 0; i < 4; ++i) a4[i] = *(const float4*)&As[tr * 4 + i][k4];
                #pragma unroll
                for (int kk = 0; kk < 4; ++kk) b4[kk] = *(const float4*)&Cs[k4 + kk][tc * 4];
                #pragma unroll
                for (int i = 0; i < 4; ++i) {
                    const float av[4] = {a4[i].x, a4[i].y, a4[i].z, a4[i].w};
                    #pragma unroll
                    for (int kk = 0; kk < 4; ++kk) {
                        acc[i].x += av[kk] * b4[kk].x;
                        acc[i].y += av[kk] * b4[kk].y;
                        acc[i].z += av[kk] * b4[kk].z;
                        acc[i].w += av[kk] * b4[kk].w;
                    }
                }
            }
            __syncthreads();
        }
        // d2 = sq_r + sq_c - 2*dot (+1e9 on diagonal), same formula as reference
        #pragma unroll
        for (int i = 0; i < 4; ++i) {
            int rl = tr * 4 + i, rg = row0 + rl;
            float sr = sqn[b * 576 + rg];
            float vv[4] = {acc[i].x, acc[i].y, acc[i].z, acc[i].w};
            #pragma unroll
            for (int j = 0; j < 4; ++j) {
                int cl = tc * 4 + j, cg = cc * 64 + cl;
                float d = sr + sqn[b * 576 + cg] - 2.f * vv[j];
                if (cg == rg) d += 1e9f;
                d2s[rl][cl] = d;
            }
        }
        __syncthreads();
        if (tid < 64) {
            for (int j = 0; j < 64; ++j) {
                float cv = d2s[tid][j];
                if (cv < tv[4]) {
                    int cidx = cc * 64 + j;
                    // stable sorted insert: strict '<' keeps earlier index on ties
                    #pragma unroll
                    for (int p = 0; p < 5; ++p) {
                        bool less = cv < tv[p];
                        float nv = less ? tv[p] : cv;
                        int ni   = less ? ti[p] : cidx;
                        tv[p] = less ? cv : tv[p];
                        ti[p] = less ? cidx : ti[p];
                        cv = nv; cidx = ni;
                    }
                }
            }
        }
        __syncthreads();
    }
    if (tid < 64) {
        int rg = b * 576 + row0 + tid;
        #pragma unroll
        for (int p = 0; p < 5; ++p) idxOut[rg * 5 + p] = b * 576 + ti[p];
    }
}

// ---------------- generic 64x64-tile f32 GEMM (head) ----------------
// EPI: 0 none, 1 +bias, 2 relu(x+bias), 3 gelu((x+bias)*g+be), 4 res + (x+bias)*g+be
template <int EPI>
__global__ __launch_bounds__(256) void gemm_rm_k(
    const float* __restrict__ A, const float* __restrict__ W, float* __restrict__ out,
    int M, int N, int K,
    const float* __restrict__ bias, const float* __restrict__ gsc,
    const float* __restrict__ gsh, const float* __restrict__ res)
{
    __shared__ float As[64][68];
    __shared__ float Ws[64][68];
    const int tid = threadIdx.x;
    const int tr = tid >> 4, tc = tid & 15;
    const int mBase = blockIdx.x * 64, nBase = blockIdx.y * 64;

    float4 acc[4];
    acc[0] = acc[1] = acc[2] = acc[3] = float4{0.f, 0.f, 0.f, 0.f};

    for (int kc = 0; kc < K; kc += 64) {
        #pragma unroll
        for (int i = 0; i < 4; ++i) {
            int q = i * 256 + tid;
            int m = q >> 4, kq = q & 15;
            *(float4*)&As[m][kq * 4] =
                *(const float4*)&A[(size_t)(mBase + m) * K + kc + kq * 4];
            *(float4*)&Ws[m][kq * 4] =
                *(const float4*)&W[(size_t)(kc + m) * N + nBase + kq * 4];
        }
        __syncthreads();
        #pragma unroll
        for (int k4 = 0; k4 < 64; k4 += 4) {
            float4 a4[4], b4[4];
            #pragma unroll
            for (int i = 0; i < 4; ++i) a4[i] = *(const float4*)&As[tr * 4 + i][k4];
            #pragma unroll
            for (int kk = 0; kk < 4; ++kk) b4[kk] = *(const float4*)&Ws[k4 + kk][tc * 4];
            #pragma unroll
            for (int i = 0; i < 4; ++i) {
                const float av[4] = {a4[i].x, a4[i].y, a4[i].z, a4[i].w};
                #pragma unroll
                for (int kk = 0; kk < 4; ++kk) {
                    acc[i].x += av[kk] * b4[kk].x;
                    acc[i].y += av[kk] * b4[kk].y;
                    acc[i].z += av[kk] * b4[kk].z;
                    acc[i].w += av[kk] * b4[kk].w;
                }
            }
        }
        __syncthreads();
    }

    #pragma unroll
    for (int i = 0; i < 4; ++i) {
        int row = mBase + tr * 4 + i;
        int n0 = nBase + tc * 4;
        float v[4] = {acc[i].x, acc[i].y, acc[i].z, acc[i].w};
        #pragma unroll
        for (int j = 0; j < 4; ++j) {
            int n = n0 + j;
            float xv = v[j];
            if (EPI == 1) xv += bias[n];
            if (EPI == 2) { xv += bias[n]; xv = fmaxf(xv, 0.f); }
            if (EPI == 3) { xv = (xv + bias[n]) * gsc[n] + gsh[n]; xv = gelu_exact(xv); }
            if (EPI == 4) {
                xv = res[(size_t)row * N + n] + (xv + bias[n]) * gsc[n] + gsh[n];
            }
            v[j] = xv;
        }
        *(float4*)&out[(size_t)row * N + n0] = float4{v[0], v[1], v[2], v[3]};
    }
}

// ---------------- 128x64-tile f32 GEMM (att path, UNCHANGED from R3) ----------------
template <int EPI>
__global__ __launch_bounds__(256) void gemm128_k(
    const float* __restrict__ A, const float* __restrict__ W, float* __restrict__ out,
    int M, int N, int K,
    const float* __restrict__ bias, const float* __restrict__ gsc,
    const float* __restrict__ gsh, const float* __restrict__ res)
{
    __shared__ float As[128][68];
    __shared__ float Ws[64][68];
    const int tid = threadIdx.x;
    const int tr = tid >> 4, tc = tid & 15;
    const int mBase = blockIdx.x * 128, nBase = blockIdx.y * 64;

    float4 acc[8];
    #pragma unroll
    for (int i = 0; i < 8; ++i) acc[i] = float4{0.f, 0.f, 0.f, 0.f};

    for (int kc = 0; kc < K; kc += 64) {
        #pragma unroll
        for (int i = 0; i < 8; ++i) {
            int q = i * 256 + tid;
            int m = q >> 4, kq = q & 15;       // m < 128
            *(float4*)&As[m][kq * 4] =
                *(const float4*)&A[(size_t)(mBase + m) * K + kc + kq * 4];
        }
        #pragma unroll
        for (int i = 0; i < 4; ++i) {
            int q = i * 256 + tid;
            int m = q >> 4, kq = q & 15;       // m < 64
            *(float4*)&Ws[m][kq * 4] =
                *(const float4*)&W[(size_t)(kc + m) * N + nBase + kq * 4];
        }
        __syncthreads();
        #pragma unroll
        for (int k4 = 0; k4 < 64; k4 += 4) {
            float4 a4[8], b4[4];
            #pragma unroll
            for (int i = 0; i < 8; ++i) a4[i] = *(const float4*)&As[tr * 8 + i][k4];
            #pragma unroll
            for (int kk = 0; kk < 4; ++kk) b4[kk] = *(const float4*)&Ws[k4 + kk][tc * 4];
            #pragma unroll
            for (int i = 0; i < 8; ++i) {
                const float av[4] = {a4[i].x, a4[i].y, a4[i].z, a4[i].w};
                #pragma unroll
                for (int kk = 0; kk < 4; ++kk) {
                    acc[i].x += av[kk] * b4[kk].x;
                    acc[i].y += av[kk] * b4[kk].y;
                    acc[i].z += av[kk] * b4[kk].z;
                    acc[i].w += av[kk] * b4[kk].w;
                }
            }
        }
        __syncthreads();
    }

    #pragma unroll
    for (int i = 0; i < 8; ++i) {
        int row = mBase + tr * 8 + i;
        int n0 = nBase + tc * 4;
        float v[4] = {acc[i].x, acc[i].y, acc[i].z, acc[i].w};
        #pragma unroll
        for (int j = 0; j < 4; ++j) {
            int n = n0 + j;
            float xv = v[j];
            if (EPI == 1) xv += bias[n];
            if (EPI == 2) { xv += bias[n]; xv = fmaxf(xv, 0.f); }
            if (EPI == 3) { xv = (xv + bias[n]) * gsc[n] + gsh[n]; xv = gelu_exact(xv); }
            if (EPI == 4) {
                xv = res[(size_t)row * N + n] + (xv + bias[n]) * gsc[n] + gsh[n];
            }
            v[j] = xv;
        }
        *(float4*)&out[(size_t)row * N + n0] = float4{v[0], v[1], v[2], v[3]};
    }
}

// ---------------- bf16 MFMA GEMM: A[M][K] bf16, Bt[N][K] bf16, out bf16 ----------------
// D tile 64x64 per block (4 waves); mfma_f32_16x16x32_bf16.
// EPI: 2 relu(x+bias), 3 gelu((x+bias)*g+be), 4 res + (x+bias)*g+be
template <int EPI>
__global__ __launch_bounds__(256) void gemm_mfma_k(
    const unsigned short* __restrict__ A, const unsigned short* __restrict__ Bt,
    unsigned short* __restrict__ out, int M, int N, int K,
    const float* __restrict__ bias, const float* __restrict__ gsc,
    const float* __restrict__ gsh, const unsigned short* __restrict__ res)
{
    using frag = __attribute__((ext_vector_type(8))) short;
    using facc = __attribute__((ext_vector_type(4))) float;
    __shared__ unsigned short As[64][72];   // [m][k], stride 144B (16B-aligned rows)
    __shared__ unsigned short Bs[64][72];   // [n][k]
    const int tid = threadIdx.x;
    const int wave = tid >> 6, lane = tid & 63;
    const int m16 = lane & 15, quad = lane >> 4;
    const int mBase = blockIdx.x * 64, nBase = blockIdx.y * 64;

    facc zero = {0.f, 0.f, 0.f, 0.f};
    facc acc[4];
    #pragma unroll
    for (int t = 0; t < 4; ++t) acc[t] = zero;

    for (int kc = 0; kc < K; kc += 64) {
        #pragma unroll
        for (int r = 0; r < 2; ++r) {
            int q = r * 256 + tid;            // 0..511
            int row = q >> 3, c8 = (q & 7) * 8;
            *(int4*)&As[row][c8] =
                *(const int4*)&A[(size_t)(mBase + row) * K + kc + c8];
            *(int4*)&Bs[row][c8] =
                *(const int4*)&Bt[(size_t)(nBase + row) * K + kc + c8];
        }
        __syncthreads();
        #pragma unroll
        for (int kk = 0; kk < 64; kk += 32) {
            frag a = *(const frag*)&As[16 * wave + m16][kk + quad * 8];
            #pragma unroll
            for (int t = 0; t < 4; ++t) {
                frag b = *(const frag*)&Bs[t * 16 + m16][kk + quad * 8];
                acc[t] = __builtin_amdgcn_mfma_f32_16x16x32_bf16(a, b, acc[t], 0, 0, 0);
            }
        }
        __syncthreads();
    }

    // C/D layout: D[quad*4+reg][lane&15] per 16x16 tile
    #pragma unroll
    for (int t = 0; t < 4; ++t) {
        #pragma unroll
        for (int r = 0; r < 4; ++r) {
            int row = mBase + 16 * wave + quad * 4 + r;
            int col = nBase + t * 16 + m16;
            float xv = acc[t][r];
            if (EPI == 2) { xv += bias[col]; xv = fmaxf(xv, 0.f); }
            if (EPI == 3) { xv = (xv + bias[col]) * gsc[col] + gsh[col]; xv = gelu_exact(xv); }
            if (EPI == 4) {
                xv = bf2f(res[(size_t)row * N + col]) + (xv + bias[col]) * gsc[col] + gsh[col];
            }
            out[(size_t)row * N + col] = f2bf(xv);
        }
    }
}

// ---------------- weight prep: f32 [K][N] -> bf16 [N][K] ----------------
__global__ __launch_bounds__(256) void wprep_k(const float* __restrict__ w,
                                               unsigned short* __restrict__ wt,
                                               int K, int N) {
    int gid = blockIdx.x * 256 + threadIdx.x;
    int n = gid / K, k = gid % K;
    wt[gid] = f2bf(w[(size_t)k * N + n]);
}

// ---------------- edge attention (UNCHANGED) ----------------
__global__ __launch_bounds__(256) void edge_att_k(
    const float* __restrict__ hA, const float* __restrict__ hB,
    const int* __restrict__ idx, const float* __restrict__ w2,
    const float* __restrict__ b2, float* __restrict__ att)
{
    int wid = threadIdx.x >> 6, lane = threadIdx.x & 63;
    int e = blockIdx.x * 4 + wid;
    int dst = e / K_;
    int src = idx[e];
    float s = 0.f;
    #pragma unroll
    for (int c0 = 0; c0 < 3; ++c0) {
        int c = lane + c0 * 64;
        float v = hA[(size_t)src * 192 + c] + hB[(size_t)dst * 192 + c];
        v = fmaxf(v, 0.f);
        s += v * w2[c];
    }
    #pragma unroll
    for (int off = 32; off; off >>= 1) s += __shfl_down(s, off);
    if (lane == 0) att[e] = 1.f / (1.f + expf(-(s + b2[0])));
}

// ---------------- message passing, bf16 out (f32 or bf16 in) ----------------
__device__ __forceinline__ float ldv(const float* p, size_t i) { return p[i]; }
__device__ __forceinline__ float ldv(const unsigned short* p, size_t i) { return bf2f(p[i]); }

template <typename TI>
__global__ __launch_bounds__(256) void msg_bf_k(
    const TI* __restrict__ h, const float* __restrict__ att,
    const int* __restrict__ idx, unsigned short* __restrict__ s)
{
    int g = blockIdx.x * 256 + threadIdx.x;  // < BN*192
    int n = g / 192, c = g % 192;
    float acc = ldv(h, (size_t)g);
    #pragma unroll
    for (int p = 0; p < K_; ++p) {
        int sp = idx[n * K_ + p];
        acc += att[n * K_ + p] * ldv(h, (size_t)sp * 192 + c);
    }
    s[g] = f2bf(acc);
}

// ---------------- global average pool over nodes (bf16 in) ----------------
__global__ void pool_bf16_k(const unsigned short* __restrict__ t, float* __restrict__ g) {
    int b = blockIdx.x, c = threadIdx.x;   // 192 threads
    float s = 0.f;
    for (int n = 0; n < 576; ++n) s += bf2f(t[((size_t)b * 576 + n) * 192 + c]);
    g[b * 192 + c] = s * (1.f / 576.f);
}

// ---------------- head reduce (UNCHANGED) ----------------
__global__ __launch_bounds__(256) void head2_k(
    const float* __restrict__ p, const float* __restrict__ w2,
    const float* __restrict__ b2, float* __restrict__ out)
{
    int b = blockIdx.x;
    float s = 0.f;
    for (int j = threadIdx.x; j < 1024; j += 256) s += p[(size_t)b * 1024 + j] * w2[j];
    #pragma unroll
    for (int off = 32; off; off >>= 1) s += __shfl_down(s, off);
    __shared__ float ls[4];
    int wid = threadIdx.x >> 6, lane = threadIdx.x & 63;
    if (lane == 0) ls[wid] = s;
    __syncthreads();
    if (threadIdx.x == 0) out[b] = ls[0] + ls[1] + ls[2] + ls[3] + b2[0];
}

// ---------------- launch ----------------
extern "C" void kernel_launch(void* const* d_in, const int* in_sizes, int n_in,
                              void* d_out, int out_size, void* d_ws, size_t ws_size,
                              hipStream_t stream) {
    const float* x        = (const float*)d_in[0];
    const float* stem_w   = (const float*)d_in[1];
    const float* stem_b   = (const float*)d_in[2];
    const float* pos      = (const float*)d_in[3];
    const float* att_w1   = (const float*)d_in[4];
    const float* att_b1   = (const float*)d_in[5];
    const float* att_w2   = (const float*)d_in[6];
    const float* att_b2   = (const float*)d_in[7];
    const float* gnn_w1   = (const float*)d_in[8];
    const float* gnn_b1   = (const float*)d_in[9];
    const float* gnn_w2   = (const float*)d_in[10];
    const float* gnn_b2   = (const float*)d_in[11];
    const float* ffn_w1   = (const float*)d_in[12];
    const float* ffn_b1   = (const float*)d_in[13];
    const float* ffn_g1   = (const float*)d_in[14];
    const float* ffn_be1  = (const float*)d_in[15];
    const float* ffn_w2   = (const float*)d_in[16];
    const float* ffn_b2   = (const float*)d_in[17];
    const float* ffn_g2   = (const float*)d_in[18];
    const float* ffn_be2  = (const float*)d_in[19];
    const float* pred_w1  = (const float*)d_in[20];
    const float* pred_b1  = (const float*)d_in[21];
    const float* pred_g   = (const float*)d_in[22];
    const float* pred_be  = (const float*)d_in[23];
    const float* pred_w2  = (const float*)d_in[24];
    const float* pred_b2  = (const float*)d_in[25];

    float* ws = (float*)d_ws;
    const size_t RSZ = (size_t)BN_ * C_;          // 7,077,888 floats
    float* R0 = ws;               // nf (f32) — live until msg layer 1
    float* R1 = R0 + RSZ;         // hA (f32) -> [Sb | Hb] bf16
    float* R2 = R1 + RSZ;         // hB (f32) -> [Tb | ToutB] bf16
    float* R3 = R2 + RSZ;         // Wt(stem) -> nfT -> Ub (bf16 FFN u-chunk)
    float* sqb = R3 + RSZ;        // BN
    int*   idxb = (int*)(sqb + BN_);              // E ints
    float* gb = (float*)(idxb + E_);              // 64*192
    float* pb = gb + 64 * C_;                     // 64*1024
    unsigned short* wg1T = (unsigned short*)(pb + 64 * 1024);  // [192][192]
    unsigned short* wg2T = wg1T + 192 * 192;
    unsigned short* wf1T = wg2T + 192 * 192;      // [768][192]
    unsigned short* wf2T = wf1T + 768 * 192;      // [192][768]

    unsigned short* Sb    = (unsigned short*)R1;             // BN x 192 bf16
    unsigned short* Hb    = (unsigned short*)(R1 + RSZ / 2);
    unsigned short* Tb    = (unsigned short*)R2;
    unsigned short* ToutB = (unsigned short*)(R2 + RSZ / 2);
    unsigned short* Ub    = (unsigned short*)R3;             // 18432 x 768 bf16

    float* att  = (float*)d_out;                  // E
    float* pred = att + E_;                       // 64

    float* Wt = R3;  // alias: used only by stem before nfT is written

    // 0. bf16 weight prep (dedicated buffers — safe at any point)
    wprep_k<<<144, 256, 0, stream>>>(gnn_w1, wg1T, 192, 192);
    wprep_k<<<144, 256, 0, stream>>>(gnn_w2, wg2T, 192, 192);
    wprep_k<<<576, 256, 0, stream>>>(ffn_w1, wf1T, 192, 768);
    wprep_k<<<576, 256, 0, stream>>>(ffn_w2, wf2T, 768, 192);

    // 1. stem
    transpose_w_k<<<576, 256, 0, stream>>>(stem_w, Wt);
    stem_gemm_k<<<dim3(576, 3), 256, 0, stream>>>(x, Wt, stem_b, pos, R0);

    // 2. kNN graph (frozen bit-sensitive path)
    sq_k<<<BN_ / 4, 256, 0, stream>>>(R0, sqb);
    transpose_nf_k<<<dim3(18, 6, 64), dim3(32, 8), 0, stream>>>(R0, R3);
    knn_topk_k<<<dim3(64, 9), 256, 0, stream>>>(R0, R3, sqb, idxb);

    // 3. edge attention (f32 — output 0 path)
    gemm128_k<0><<<dim3(288, 3), 256, 0, stream>>>(R0, att_w1, R1,
        BN_, 192, 192, nullptr, nullptr, nullptr, nullptr);
    gemm128_k<1><<<dim3(288, 3), 256, 0, stream>>>(R0, att_w1 + 192 * 192, R2,
        BN_, 192, 192, att_b1, nullptr, nullptr, nullptr);
    edge_att_k<<<E_ / 4, 256, 0, stream>>>(R1, R2, idxb, att_w2, att_b2, att);

    // 4. GNN layer 1 (bf16 MFMA)
    msg_bf_k<float><<<BN_ * C_ / 256, 256, 0, stream>>>(R0, att, idxb, Sb);
    gemm_mfma_k<2><<<dim3(576, 3), 256, 0, stream>>>(Sb, wg1T, Hb,
        BN_, 192, 192, gnn_b1, nullptr, nullptr, nullptr);
    // 5. GNN layer 2
    msg_bf_k<unsigned short><<<BN_ * C_ / 256, 256, 0, stream>>>(Hb, att, idxb, Sb);
    gemm_mfma_k<2><<<dim3(576, 3), 256, 0, stream>>>(Sb, wg2T, Tb,
        BN_, 192, 192, gnn_b2, nullptr, nullptr, nullptr);

    // 6. FFN in 2 node-chunks of 18432 (u chunk = Ub in R3; nfT dead)
    for (int ch = 0; ch < 2; ++ch) {
        const unsigned short* Ain = Tb + (size_t)ch * 18432 * 192;
        unsigned short* Tout = ToutB + (size_t)ch * 18432 * 192;
        gemm_mfma_k<3><<<dim3(288, 12), 256, 0, stream>>>(Ain, wf1T, Ub,
            18432, 768, 192, ffn_b1, ffn_g1, ffn_be1, nullptr);
        gemm_mfma_k<4><<<dim3(288, 3), 256, 0, stream>>>(Ub, wf2T, Tout,
            18432, 192, 768, ffn_b2, ffn_g2, ffn_be2, Ain);
    }

    // 7. pool + head (f32, tiny)
    pool_bf16_k<<<64, 192, 0, stream>>>(ToutB, gb);
    gemm_rm_k<3><<<dim3(1, 16), 256, 0, stream>>>(gb, pred_w1, pb,
        64, 1024, 192, pred_b1, pred_g, pred_be, nullptr);
    head2_k<<<64, 256, 0, stream>>>(pb, pred_w2, pred_b2, pred);
}

// Round 5
// 897.262 us; speedup vs baseline: 1.4443x; 1.0227x over previous
//
#include <hip/hip_runtime.h>
#include <hip/hip_bf16.h>
#include <math.h>

// ---------------- problem constants ----------------
constexpr int B_    = 64;
constexpr int C_    = 192;
constexpr int N_    = 576;    // nodes per image (24x24)
constexpr int BN_   = B_ * N_;      // 36864
constexpr int K_    = 5;
constexpr int E_    = BN_ * K_;     // 184320

__device__ __forceinline__ float gelu_exact(float x) {
    return 0.5f * x * (1.0f + erff(x * 0.70710678118654752440f));
}

__device__ __forceinline__ float bf2f(unsigned short v) {
    return __uint_as_float(((unsigned)v) << 16);
}
__device__ __forceinline__ unsigned short f2bf(float x) {
    __hip_bfloat16 h = __float2bfloat16(x);
    return *(unsigned short*)&h;
}

// ---------------- tiny transpose: stem_w [192][768] -> Wt [768][192] ----------------
__global__ __launch_bounds__(256) void transpose_w_k(const float* __restrict__ w,
                                                     float* __restrict__ wt) {
    int gid = blockIdx.x * 256 + threadIdx.x;      // 147456 total
    int k = gid / 192, oc = gid % 192;
    wt[gid] = w[oc * 768 + k];                     // writes coalesced
}

// ---------------- stem: 96-row tile patch-embed GEMM — SAME per-element FMA chain as R1 ----------------
__global__ __launch_bounds__(256) void stem_gemm96_k(
    const float* __restrict__ x, const float* __restrict__ Wt,
    const float* __restrict__ sb, const float* __restrict__ pos,
    float* __restrict__ nf)
{
    __shared__ float As[96][68];
    __shared__ float Ws[64][68];
    const int tid = threadIdx.x;
    const int tr = tid >> 4, tc = tid & 15;
    const int mb = blockIdx.x;          // 0..383 (64 images x 6 tiles of 96)
    const int nb = blockIdx.y;          // 0..2 oc blocks
    const int b  = mb / 6;
    const int n0 = (mb % 6) * 96;       // node offset within image

    float4 acc[6];
    #pragma unroll
    for (int i = 0; i < 6; ++i) acc[i] = float4{0.f, 0.f, 0.f, 0.f};

    for (int kc = 0; kc < 768; kc += 64) {
        #pragma unroll
        for (int i = 0; i < 6; ++i) {
            int q = i * 256 + tid;
            int m = q >> 4, kq = q & 15;       // m < 96
            int k = kc + kq * 4;
            int ci = k >> 8, rem = k & 255, dy = rem >> 4, dx = rem & 15;
            int n = n0 + m, py = n / 24, px = n % 24;
            const float* src = &x[(((size_t)(b * 3 + ci) * 384) + py * 16 + dy) * 384
                                  + px * 16 + dx];
            *(float4*)&As[m][kq * 4] = *(const float4*)src;
        }
        #pragma unroll
        for (int i = 0; i < 4; ++i) {
            int q = i * 256 + tid;
            int m = q >> 4, kq = q & 15;       // m < 64
            *(float4*)&Ws[m][kq * 4] =
                *(const float4*)&Wt[(size_t)(kc + m) * 192 + nb * 64 + kq * 4];
        }
        __syncthreads();
        #pragma unroll
        for (int k4 = 0; k4 < 64; k4 += 4) {
            float4 a4[6], b4[4];
            #pragma unroll
            for (int i = 0; i < 6; ++i) a4[i] = *(const float4*)&As[tr * 6 + i][k4];
            #pragma unroll
            for (int kk = 0; kk < 4; ++kk) b4[kk] = *(const float4*)&Ws[k4 + kk][tc * 4];
            #pragma unroll
            for (int i = 0; i < 6; ++i) {
                const float av[4] = {a4[i].x, a4[i].y, a4[i].z, a4[i].w};
                #pragma unroll
                for (int kk = 0; kk < 4; ++kk) {
                    acc[i].x += av[kk] * b4[kk].x;
                    acc[i].y += av[kk] * b4[kk].y;
                    acc[i].z += av[kk] * b4[kk].z;
                    acc[i].w += av[kk] * b4[kk].w;
                }
            }
        }
        __syncthreads();
    }

    #pragma unroll
    for (int i = 0; i < 6; ++i) {
        int n = n0 + tr * 6 + i;
        int row = b * 576 + n;
        int oc0 = nb * 64 + tc * 4;
        float v[4] = {acc[i].x, acc[i].y, acc[i].z, acc[i].w};
        #pragma unroll
        for (int j = 0; j < 4; ++j) {
            int oc = oc0 + j;
            v[j] = v[j] + sb[oc] + pos[oc * 576 + n];
        }
        *(float4*)&nf[(size_t)row * 192 + oc0] = float4{v[0], v[1], v[2], v[3]};
    }
}

// ---------------- sq norms per node (UNCHANGED) ----------------
__global__ __launch_bounds__(256) void sq_k(const float* __restrict__ nf,
                                            float* __restrict__ sq) {
    int wid = threadIdx.x >> 6, lane = threadIdx.x & 63;
    int n = blockIdx.x * 4 + wid;
    const float* row = nf + (size_t)n * 192;
    float s = 0.f;
    #pragma unroll
    for (int c = 0; c < 3; ++c) { float v = row[lane + c * 64]; s += v * v; }
    #pragma unroll
    for (int off = 32; off; off >>= 1) s += __shfl_down(s, off);
    if (lane == 0) sq[n] = s;
}

// ---------------- transpose nf per image (UNCHANGED) ----------------
__global__ void transpose_nf_k(const float* __restrict__ nf, float* __restrict__ nfT) {
    __shared__ float tile[32][33];
    int b = blockIdx.z;
    int n0 = blockIdx.x * 32, c0 = blockIdx.y * 32;
    int tx = threadIdx.x, ty = threadIdx.y;   // 32 x 8
    #pragma unroll
    for (int r = 0; r < 4; ++r) {
        int i = ty * 4 + r;
        tile[i][tx] = nf[((size_t)b * 576 + n0 + i) * 192 + c0 + tx];
    }
    __syncthreads();
    #pragma unroll
    for (int r = 0; r < 4; ++r) {
        int i = ty * 4 + r;
        nfT[((size_t)b * 192 + c0 + i) * 576 + n0 + tx] = tile[tx][i];
    }
}

// ---------------- kNN: Gram tile + running top-5 (UNCHANGED — bit-sensitive) ----------------
__global__ __launch_bounds__(256) void knn_topk_k(
    const float* __restrict__ nf, const float* __restrict__ nfT,
    const float* __restrict__ sqn, int* __restrict__ idxOut)
{
    __shared__ float As[64][68];
    __shared__ float Cs[64][68];
    __shared__ float d2s[64][68];
    const int tid = threadIdx.x;
    const int tr = tid >> 4, tc = tid & 15;
    const int b = blockIdx.x;
    const int row0 = blockIdx.y * 64;

    float tv[5];
    int ti[5];
    #pragma unroll
    for (int p = 0; p < 5; ++p) { tv[p] = 3.4e38f; ti[p] = 0; }

    for (int cc = 0; cc < 9; ++cc) {
        float4 acc[4];
        acc[0] = acc[1] = acc[2] = acc[3] = float4{0.f, 0.f, 0.f, 0.f};
        for (int kc = 0; kc < 192; kc += 64) {
            #pragma unroll
            for (int i = 0; i < 4; ++i) {
                int q = i * 256 + tid;
                int m = q >> 4, kq = q & 15;
                *(float4*)&As[m][kq * 4] =
                    *(const float4*)&nf[((size_t)(b * 576 + row0 + m)) * 192 + kc + kq * 4];
                *(float4*)&Cs[m][kq * 4] =
                    *(const float4*)&nfT[((size_t)(b * 192 + kc + m)) * 576 + cc * 64 + kq * 4];
            }
            __syncthreads();
            #pragma unroll
            for (int k4 = 0; k4 < 64; k4 += 4) {
                float4 a4[4], b4[4];
                #pragma unroll
                for (int i = 0; i < 4; ++i) a4[i] = *(const float4*)&As[tr * 4 + i][k4];
                #pragma unroll
                for (int kk = 0; kk < 4; ++kk) b4[kk] = *(const float4*)&Cs[k4 + kk][tc * 4];
                #pragma unroll
                for (int i = 0; i < 4; ++i) {
                    const float av[4] = {a4[i].x, a4[i].y, a4[i].z, a4[i].w};
                    #pragma unroll
                    for (int kk = 0; kk < 4; ++kk) {
                        acc[i].x += av[kk] * b4[kk].x;
                        acc[i].y += av[kk] * b4[kk].y;
                        acc[i].z += av[kk] * b4[kk].z;
                        acc[i].w += av[kk] * b4[kk].w;
                    }
                }
            }
            __syncthreads();
        }
        // d2 = sq_r + sq_c - 2*dot (+1e9 on diagonal), same formula as reference
        #pragma unroll
        for (int i = 0; i < 4; ++i) {
            int rl = tr * 4 + i, rg = row0 + rl;
            float sr = sqn[b * 576 + rg];
            float vv[4] = {acc[i].x, acc[i].y, acc[i].z, acc[i].w};
            #pragma unroll
            for (int j = 0; j < 4; ++j) {
                int cl = tc * 4 + j, cg = cc * 64 + cl;
                float d = sr + sqn[b * 576 + cg] - 2.f * vv[j];
                if (cg == rg) d += 1e9f;
                d2s[rl][cl] = d;
            }
        }
        __syncthreads();
        if (tid < 64) {
            for (int j = 0; j < 64; ++j) {
                float cv = d2s[tid][j];
                if (cv < tv[4]) {
                    int cidx = cc * 64 + j;
                    // stable sorted insert: strict '<' keeps earlier index on ties
                    #pragma unroll
                    for (int p = 0; p < 5; ++p) {
                        bool less = cv < tv[p];
                        float nv = less ? tv[p] : cv;
                        int ni   = less ? ti[p] : cidx;
                        tv[p] = less ? cv : tv[p];
                        ti[p] = less ? cidx : ti[p];
                        cv = nv; cidx = ni;
                    }
                }
            }
        }
        __syncthreads();
    }
    if (tid < 64) {
        int rg = b * 576 + row0 + tid;
        #pragma unroll
        for (int p = 0; p < 5; ++p) idxOut[rg * 5 + p] = b * 576 + ti[p];
    }
}

// ---------------- generic 64x64-tile f32 GEMM (head) ----------------
// EPI: 0 none, 1 +bias, 2 relu(x+bias), 3 gelu((x+bias)*g+be), 4 res + (x+bias)*g+be
template <int EPI>
__global__ __launch_bounds__(256) void gemm_rm_k(
    const float* __restrict__ A, const float* __restrict__ W, float* __restrict__ out,
    int M, int N, int K,
    const float* __restrict__ bias, const float* __restrict__ gsc,
    const float* __restrict__ gsh, const float* __restrict__ res)
{
    __shared__ float As[64][68];
    __shared__ float Ws[64][68];
    const int tid = threadIdx.x;
    const int tr = tid >> 4, tc = tid & 15;
    const int mBase = blockIdx.x * 64, nBase = blockIdx.y * 64;

    float4 acc[4];
    acc[0] = acc[1] = acc[2] = acc[3] = float4{0.f, 0.f, 0.f, 0.f};

    for (int kc = 0; kc < K; kc += 64) {
        #pragma unroll
        for (int i = 0; i < 4; ++i) {
            int q = i * 256 + tid;
            int m = q >> 4, kq = q & 15;
            *(float4*)&As[m][kq * 4] =
                *(const float4*)&A[(size_t)(mBase + m) * K + kc + kq * 4];
            *(float4*)&Ws[m][kq * 4] =
                *(const float4*)&W[(size_t)(kc + m) * N + nBase + kq * 4];
        }
        __syncthreads();
        #pragma unroll
        for (int k4 = 0; k4 < 64; k4 += 4) {
            float4 a4[4], b4[4];
            #pragma unroll
            for (int i = 0; i < 4; ++i) a4[i] = *(const float4*)&As[tr * 4 + i][k4];
            #pragma unroll
            for (int kk = 0; kk < 4; ++kk) b4[kk] = *(const float4*)&Ws[k4 + kk][tc * 4];
            #pragma unroll
            for (int i = 0; i < 4; ++i) {
                const float av[4] = {a4[i].x, a4[i].y, a4[i].z, a4[i].w};
                #pragma unroll
                for (int kk = 0; kk < 4; ++kk) {
                    acc[i].x += av[kk] * b4[kk].x;
                    acc[i].y += av[kk] * b4[kk].y;
                    acc[i].z += av[kk] * b4[kk].z;
                    acc[i].w += av[kk] * b4[kk].w;
                }
            }
        }
        __syncthreads();
    }

    #pragma unroll
    for (int i = 0; i < 4; ++i) {
        int row = mBase + tr * 4 + i;
        int n0 = nBase + tc * 4;
        float v[4] = {acc[i].x, acc[i].y, acc[i].z, acc[i].w};
        #pragma unroll
        for (int j = 0; j < 4; ++j) {
            int n = n0 + j;
            float xv = v[j];
            if (EPI == 1) xv += bias[n];
            if (EPI == 2) { xv += bias[n]; xv = fmaxf(xv, 0.f); }
            if (EPI == 3) { xv = (xv + bias[n]) * gsc[n] + gsh[n]; xv = gelu_exact(xv); }
            if (EPI == 4) {
                xv = res[(size_t)row * N + n] + (xv + bias[n]) * gsc[n] + gsh[n];
            }
            v[j] = xv;
        }
        *(float4*)&out[(size_t)row * N + n0] = float4{v[0], v[1], v[2], v[3]};
    }
}

// ---------------- bf16 MFMA GEMM: A[M][K] bf16, Bt[N][K] bf16, out bf16 (UNCHANGED) ----------------
template <int EPI>
__global__ __launch_bounds__(256) void gemm_mfma_k(
    const unsigned short* __restrict__ A, const unsigned short* __restrict__ Bt,
    unsigned short* __restrict__ out, int M, int N, int K,
    const float* __restrict__ bias, const float* __restrict__ gsc,
    const float* __restrict__ gsh, const unsigned short* __restrict__ res)
{
    using frag = __attribute__((ext_vector_type(8))) short;
    using facc = __attribute__((ext_vector_type(4))) float;
    __shared__ unsigned short As[64][72];   // [m][k]
    __shared__ unsigned short Bs[64][72];   // [n][k]
    const int tid = threadIdx.x;
    const int wave = tid >> 6, lane = tid & 63;
    const int m16 = lane & 15, quad = lane >> 4;
    const int mBase = blockIdx.x * 64, nBase = blockIdx.y * 64;

    facc zero = {0.f, 0.f, 0.f, 0.f};
    facc acc[4];
    #pragma unroll
    for (int t = 0; t < 4; ++t) acc[t] = zero;

    for (int kc = 0; kc < K; kc += 64) {
        #pragma unroll
        for (int r = 0; r < 2; ++r) {
            int q = r * 256 + tid;            // 0..511
            int row = q >> 3, c8 = (q & 7) * 8;
            *(int4*)&As[row][c8] =
                *(const int4*)&A[(size_t)(mBase + row) * K + kc + c8];
            *(int4*)&Bs[row][c8] =
                *(const int4*)&Bt[(size_t)(nBase + row) * K + kc + c8];
        }
        __syncthreads();
        #pragma unroll
        for (int kk = 0; kk < 64; kk += 32) {
            frag a = *(const frag*)&As[16 * wave + m16][kk + quad * 8];
            #pragma unroll
            for (int t = 0; t < 4; ++t) {
                frag b = *(const frag*)&Bs[t * 16 + m16][kk + quad * 8];
                acc[t] = __builtin_amdgcn_mfma_f32_16x16x32_bf16(a, b, acc[t], 0, 0, 0);
            }
        }
        __syncthreads();
    }

    #pragma unroll
    for (int t = 0; t < 4; ++t) {
        #pragma unroll
        for (int r = 0; r < 4; ++r) {
            int row = mBase + 16 * wave + quad * 4 + r;
            int col = nBase + t * 16 + m16;
            float xv = acc[t][r];
            if (EPI == 2) { xv += bias[col]; xv = fmaxf(xv, 0.f); }
            if (EPI == 3) { xv = (xv + bias[col]) * gsc[col] + gsh[col]; xv = gelu_exact(xv); }
            if (EPI == 4) {
                xv = bf2f(res[(size_t)row * N + col]) + (xv + bias[col]) * gsc[col] + gsh[col];
            }
            out[(size_t)row * N + col] = f2bf(xv);
        }
    }
}

// ---------------- split-bf16 MFMA GEMM (f32-accurate): out f32; EPI 0 none, 1 +bias ----------------
template <int EPI>
__global__ __launch_bounds__(256) void gemm_mfma_split_k(
    const unsigned short* __restrict__ Ah, const unsigned short* __restrict__ Al,
    const unsigned short* __restrict__ Bh, const unsigned short* __restrict__ Bl,
    float* __restrict__ out, int M, int N, int K, const float* __restrict__ bias)
{
    using frag = __attribute__((ext_vector_type(8))) short;
    using facc = __attribute__((ext_vector_type(4))) float;
    __shared__ unsigned short AsH[64][72], AsL[64][72];
    __shared__ unsigned short BsH[64][72], BsL[64][72];
    const int tid = threadIdx.x;
    const int wave = tid >> 6, lane = tid & 63;
    const int m16 = lane & 15, quad = lane >> 4;
    const int mBase = blockIdx.x * 64, nBase = blockIdx.y * 64;

    facc zero = {0.f, 0.f, 0.f, 0.f};
    facc acc[4];
    #pragma unroll
    for (int t = 0; t < 4; ++t) acc[t] = zero;

    for (int kc = 0; kc < K; kc += 64) {
        #pragma unroll
        for (int r = 0; r < 2; ++r) {
            int q = r * 256 + tid;
            int row = q >> 3, c8 = (q & 7) * 8;
            *(int4*)&AsH[row][c8] = *(const int4*)&Ah[(size_t)(mBase + row) * K + kc + c8];
            *(int4*)&AsL[row][c8] = *(const int4*)&Al[(size_t)(mBase + row) * K + kc + c8];
            *(int4*)&BsH[row][c8] = *(const int4*)&Bh[(size_t)(nBase + row) * K + kc + c8];
            *(int4*)&BsL[row][c8] = *(const int4*)&Bl[(size_t)(nBase + row) * K + kc + c8];
        }
        __syncthreads();
        #pragma unroll
        for (int kk = 0; kk < 64; kk += 32) {
            frag ah = *(const frag*)&AsH[16 * wave + m16][kk + quad * 8];
            frag al = *(const frag*)&AsL[16 * wave + m16][kk + quad * 8];
            #pragma unroll
            for (int t = 0; t < 4; ++t) {
                frag bh = *(const frag*)&BsH[t * 16 + m16][kk + quad * 8];
                frag bl = *(const frag*)&BsL[t * 16 + m16][kk + quad * 8];
                acc[t] = __builtin_amdgcn_mfma_f32_16x16x32_bf16(ah, bh, acc[t], 0, 0, 0);
                acc[t] = __builtin_amdgcn_mfma_f32_16x16x32_bf16(ah, bl, acc[t], 0, 0, 0);
                acc[t] = __builtin_amdgcn_mfma_f32_16x16x32_bf16(al, bh, acc[t], 0, 0, 0);
            }
        }
        __syncthreads();
    }

    #pragma unroll
    for (int t = 0; t < 4; ++t) {
        #pragma unroll
        for (int r = 0; r < 4; ++r) {
            int row = mBase + 16 * wave + quad * 4 + r;
            int col = nBase + t * 16 + m16;
            float xv = acc[t][r];
            if (EPI == 1) xv += bias[col];
            out[(size_t)row * N + col] = xv;
        }
    }
}

// ---------------- split prep: f32 -> (hi, lo) bf16 ----------------
__global__ __launch_bounds__(256) void asplit_k(const float* __restrict__ a,
                                                unsigned short* __restrict__ hi,
                                                unsigned short* __restrict__ lo) {
    int g = blockIdx.x * 256 + threadIdx.x;
    float v = a[g];
    unsigned short h = f2bf(v);
    hi[g] = h;
    lo[g] = f2bf(v - bf2f(h));
}

// att_w1 [384][192] -> split-transposed [2][192 n][192 k]
__global__ __launch_bounds__(256) void wsplit_att_k(const float* __restrict__ w,
                                                    unsigned short* __restrict__ hi,
                                                    unsigned short* __restrict__ lo) {
    int gid = blockIdx.x * 256 + threadIdx.x;    // < 73728
    int half = gid / 36864, r = gid % 36864;
    int n = r / 192, k = r % 192;
    float v = w[(size_t)(half * 192 + k) * 192 + n];
    unsigned short h = f2bf(v);
    hi[gid] = h;
    lo[gid] = f2bf(v - bf2f(h));
}

// ---------------- weight prep: f32 [K][N] -> bf16 [N][K] ----------------
__global__ __launch_bounds__(256) void wprep_k(const float* __restrict__ w,
                                               unsigned short* __restrict__ wt,
                                               int K, int N) {
    int gid = blockIdx.x * 256 + threadIdx.x;
    int n = gid / K, k = gid % K;
    wt[gid] = f2bf(w[(size_t)k * N + n]);
}

// ---------------- edge attention (UNCHANGED) ----------------
__global__ __launch_bounds__(256) void edge_att_k(
    const float* __restrict__ hA, const float* __restrict__ hB,
    const int* __restrict__ idx, const float* __restrict__ w2,
    const float* __restrict__ b2, float* __restrict__ att)
{
    int wid = threadIdx.x >> 6, lane = threadIdx.x & 63;
    int e = blockIdx.x * 4 + wid;
    int dst = e / K_;
    int src = idx[e];
    float s = 0.f;
    #pragma unroll
    for (int c0 = 0; c0 < 3; ++c0) {
        int c = lane + c0 * 64;
        float v = hA[(size_t)src * 192 + c] + hB[(size_t)dst * 192 + c];
        v = fmaxf(v, 0.f);
        s += v * w2[c];
    }
    #pragma unroll
    for (int off = 32; off; off >>= 1) s += __shfl_down(s, off);
    if (lane == 0) att[e] = 1.f / (1.f + expf(-(s + b2[0])));
}

// ---------------- message passing, bf16 out (f32 or bf16 in) ----------------
__device__ __forceinline__ float ldv(const float* p, size_t i) { return p[i]; }
__device__ __forceinline__ float ldv(const unsigned short* p, size_t i) { return bf2f(p[i]); }

template <typename TI>
__global__ __launch_bounds__(256) void msg_bf_k(
    const TI* __restrict__ h, const float* __restrict__ att,
    const int* __restrict__ idx, unsigned short* __restrict__ s)
{
    int g = blockIdx.x * 256 + threadIdx.x;  // < BN*192
    int n = g / 192, c = g % 192;
    float acc = ldv(h, (size_t)g);
    #pragma unroll
    for (int p = 0; p < K_; ++p) {
        int sp = idx[n * K_ + p];
        acc += att[n * K_ + p] * ldv(h, (size_t)sp * 192 + c);
    }
    s[g] = f2bf(acc);
}

// ---------------- global average pool over nodes (bf16 in) ----------------
__global__ void pool_bf16_k(const unsigned short* __restrict__ t, float* __restrict__ g) {
    int b = blockIdx.x, c = threadIdx.x;   // 192 threads
    float s = 0.f;
    for (int n = 0; n < 576; ++n) s += bf2f(t[((size_t)b * 576 + n) * 192 + c]);
    g[b * 192 + c] = s * (1.f / 576.f);
}

// ---------------- head reduce (UNCHANGED) ----------------
__global__ __launch_bounds__(256) void head2_k(
    const float* __restrict__ p, const float* __restrict__ w2,
    const float* __restrict__ b2, float* __restrict__ out)
{
    int b = blockIdx.x;
    float s = 0.f;
    for (int j = threadIdx.x; j < 1024; j += 256) s += p[(size_t)b * 1024 + j] * w2[j];
    #pragma unroll
    for (int off = 32; off; off >>= 1) s += __shfl_down(s, off);
    __shared__ float ls[4];
    int wid = threadIdx.x >> 6, lane = threadIdx.x & 63;
    if (lane == 0) ls[wid] = s;
    __syncthreads();
    if (threadIdx.x == 0) out[b] = ls[0] + ls[1] + ls[2] + ls[3] + b2[0];
}

// ---------------- launch ----------------
extern "C" void kernel_launch(void* const* d_in, const int* in_sizes, int n_in,
                              void* d_out, int out_size, void* d_ws, size_t ws_size,
                              hipStream_t stream) {
    const float* x        = (const float*)d_in[0];
    const float* stem_w   = (const float*)d_in[1];
    const float* stem_b   = (const float*)d_in[2];
    const float* pos      = (const float*)d_in[3];
    const float* att_w1   = (const float*)d_in[4];
    const float* att_b1   = (const float*)d_in[5];
    const float* att_w2   = (const float*)d_in[6];
    const float* att_b2   = (const float*)d_in[7];
    const float* gnn_w1   = (const float*)d_in[8];
    const float* gnn_b1   = (const float*)d_in[9];
    const float* gnn_w2   = (const float*)d_in[10];
    const float* gnn_b2   = (const float*)d_in[11];
    const float* ffn_w1   = (const float*)d_in[12];
    const float* ffn_b1   = (const float*)d_in[13];
    const float* ffn_g1   = (const float*)d_in[14];
    const float* ffn_be1  = (const float*)d_in[15];
    const float* ffn_w2   = (const float*)d_in[16];
    const float* ffn_b2   = (const float*)d_in[17];
    const float* ffn_g2   = (const float*)d_in[18];
    const float* ffn_be2  = (const float*)d_in[19];
    const float* pred_w1  = (const float*)d_in[20];
    const float* pred_b1  = (const float*)d_in[21];
    const float* pred_g   = (const float*)d_in[22];
    const float* pred_be  = (const float*)d_in[23];
    const float* pred_w2  = (const float*)d_in[24];
    const float* pred_b2  = (const float*)d_in[25];

    float* ws = (float*)d_ws;
    const size_t RSZ = (size_t)BN_ * C_;          // 7,077,888 floats
    float* R0 = ws;               // nf (f32) — live until msg layer 1
    float* R1 = R0 + RSZ;         // hA (f32) -> [Sb | Hb] bf16
    float* R2 = R1 + RSZ;         // hB (f32) -> [Tb | ToutB] bf16
    float* R3 = R2 + RSZ;         // Wt(stem) -> nfT -> [Ahi|Alo] -> Ub
    float* sqb = R3 + RSZ;        // BN
    int*   idxb = (int*)(sqb + BN_);              // E ints
    float* gb = (float*)(idxb + E_);              // 64*192
    float* pb = gb + 64 * C_;                     // 64*1024
    unsigned short* wg1T = (unsigned short*)(pb + 64 * 1024);  // [192][192]
    unsigned short* wg2T = wg1T + 192 * 192;
    unsigned short* wf1T = wg2T + 192 * 192;      // [768][192]
    unsigned short* wf2T = wf1T + 768 * 192;      // [192][768]
    unsigned short* waHi = wf2T + 192 * 768;      // [2][192][192]
    unsigned short* waLo = waHi + 2 * 192 * 192;

    unsigned short* Sb    = (unsigned short*)R1;             // BN x 192 bf16
    unsigned short* Hb    = (unsigned short*)(R1 + RSZ / 2);
    unsigned short* Tb    = (unsigned short*)R2;
    unsigned short* ToutB = (unsigned short*)(R2 + RSZ / 2);
    unsigned short* Ahi   = (unsigned short*)R3;             // after nfT is dead
    unsigned short* Alo   = Ahi + RSZ;
    unsigned short* Ub    = (unsigned short*)R3;             // FFN u-chunk (after att)

    float* att  = (float*)d_out;                  // E
    float* pred = att + E_;                       // 64

    float* Wt = R3;  // alias: used only by stem before nfT is written

    // 0. bf16 weight prep
    wprep_k<<<144, 256, 0, stream>>>(gnn_w1, wg1T, 192, 192);
    wprep_k<<<144, 256, 0, stream>>>(gnn_w2, wg2T, 192, 192);
    wprep_k<<<576, 256, 0, stream>>>(ffn_w1, wf1T, 192, 768);
    wprep_k<<<576, 256, 0, stream>>>(ffn_w2, wf2T, 768, 192);
    wsplit_att_k<<<288, 256, 0, stream>>>(att_w1, waHi, waLo);

    // 1. stem (96-row tile, bit-identical FMA chain)
    transpose_w_k<<<576, 256, 0, stream>>>(stem_w, Wt);
    stem_gemm96_k<<<dim3(384, 3), 256, 0, stream>>>(x, Wt, stem_b, pos, R0);

    // 2. kNN graph (frozen bit-sensitive path)
    sq_k<<<BN_ / 4, 256, 0, stream>>>(R0, sqb);
    transpose_nf_k<<<dim3(18, 6, 64), dim3(32, 8), 0, stream>>>(R0, R3);
    knn_topk_k<<<dim3(64, 9), 256, 0, stream>>>(R0, R3, sqb, idxb);

    // 3. edge attention — split-bf16 MFMA (f32-accurate within ~1e-4)
    asplit_k<<<BN_ * C_ / 256, 256, 0, stream>>>(R0, Ahi, Alo);
    gemm_mfma_split_k<0><<<dim3(576, 3), 256, 0, stream>>>(Ahi, Alo,
        waHi, waLo, R1, BN_, 192, 192, nullptr);
    gemm_mfma_split_k<1><<<dim3(576, 3), 256, 0, stream>>>(Ahi, Alo,
        waHi + 36864, waLo + 36864, R2, BN_, 192, 192, att_b1);
    edge_att_k<<<E_ / 4, 256, 0, stream>>>(R1, R2, idxb, att_w2, att_b2, att);

    // 4. GNN layer 1 (bf16 MFMA)
    msg_bf_k<float><<<BN_ * C_ / 256, 256, 0, stream>>>(R0, att, idxb, Sb);
    gemm_mfma_k<2><<<dim3(576, 3), 256, 0, stream>>>(Sb, wg1T, Hb,
        BN_, 192, 192, gnn_b1, nullptr, nullptr, nullptr);
    // 5. GNN layer 2
    msg_bf_k<unsigned short><<<BN_ * C_ / 256, 256, 0, stream>>>(Hb, att, idxb, Sb);
    gemm_mfma_k<2><<<dim3(576, 3), 256, 0, stream>>>(Sb, wg2T, Tb,
        BN_, 192, 192, gnn_b2, nullptr, nullptr, nullptr);

    // 6. FFN in 2 node-chunks of 18432 (u chunk = Ub in R3; Ahi/Alo dead)
    for (int ch = 0; ch < 2; ++ch) {
        const unsigned short* Ain = Tb + (size_t)ch * 18432 * 192;
        unsigned short* Tout = ToutB + (size_t)ch * 18432 * 192;
        gemm_mfma_k<3><<<dim3(288, 12), 256, 0, stream>>>(Ain, wf1T, Ub,
            18432, 768, 192, ffn_b1, ffn_g1, ffn_be1, nullptr);
        gemm_mfma_k<4><<<dim3(288, 3), 256, 0, stream>>>(Ub, wf2T, Tout,
            18432, 192, 768, ffn_b2, ffn_g2, ffn_be2, Ain);
    }

    // 7. pool + head (f32, tiny)
    pool_bf16_k<<<64, 192, 0, stream>>>(ToutB, gb);
    gemm_rm_k<3><<<dim3(1, 16), 256, 0, stream>>>(gb, pred_w1, pb,
        64, 1024, 192, pred_b1, pred_g, pred_be, nullptr);
    head2_k<<<64, 256, 0, stream>>>(pb, pred_w2, pred_b2, pred);
}

// Round 6
// 877.291 us; speedup vs baseline: 1.4772x; 1.0228x over previous
//
#include <hip/hip_runtime.h>
#include <hip/hip_bf16.h>
#include <math.h>

// ---------------- problem constants ----------------
constexpr int B_    = 64;
constexpr int C_    = 192;
constexpr int N_    = 576;    // nodes per image (24x24)
constexpr int BN_   = B_ * N_;      // 36864
constexpr int K_    = 5;
constexpr int E_    = BN_ * K_;     // 184320

__device__ __forceinline__ float gelu_exact(float x) {
    return 0.5f * x * (1.0f + erff(x * 0.70710678118654752440f));
}

__device__ __forceinline__ float bf2f(unsigned short v) {
    return __uint_as_float(((unsigned)v) << 16);
}
__device__ __forceinline__ unsigned short f2bf(float x) {
    __hip_bfloat16 h = __float2bfloat16(x);
    return *(unsigned short*)&h;
}

// ---------------- tiny transpose: stem_w [192][768] -> Wt [768][192] ----------------
__global__ __launch_bounds__(256) void transpose_w_k(const float* __restrict__ w,
                                                     float* __restrict__ wt) {
    int gid = blockIdx.x * 256 + threadIdx.x;      // 147456 total
    int k = gid / 192, oc = gid % 192;
    wt[gid] = w[oc * 768 + k];                     // writes coalesced
}

// ---------------- stem: 96-row tile patch-embed GEMM (UNCHANGED from R5) ----------------
__global__ __launch_bounds__(256) void stem_gemm96_k(
    const float* __restrict__ x, const float* __restrict__ Wt,
    const float* __restrict__ sb, const float* __restrict__ pos,
    float* __restrict__ nf)
{
    __shared__ float As[96][68];
    __shared__ float Ws[64][68];
    const int tid = threadIdx.x;
    const int tr = tid >> 4, tc = tid & 15;
    const int mb = blockIdx.x;          // 0..383 (64 images x 6 tiles of 96)
    const int nb = blockIdx.y;          // 0..2 oc blocks
    const int b  = mb / 6;
    const int n0 = (mb % 6) * 96;       // node offset within image

    float4 acc[6];
    #pragma unroll
    for (int i = 0; i < 6; ++i) acc[i] = float4{0.f, 0.f, 0.f, 0.f};

    for (int kc = 0; kc < 768; kc += 64) {
        #pragma unroll
        for (int i = 0; i < 6; ++i) {
            int q = i * 256 + tid;
            int m = q >> 4, kq = q & 15;       // m < 96
            int k = kc + kq * 4;
            int ci = k >> 8, rem = k & 255, dy = rem >> 4, dx = rem & 15;
            int n = n0 + m, py = n / 24, px = n % 24;
            const float* src = &x[(((size_t)(b * 3 + ci) * 384) + py * 16 + dy) * 384
                                  + px * 16 + dx];
            *(float4*)&As[m][kq * 4] = *(const float4*)src;
        }
        #pragma unroll
        for (int i = 0; i < 4; ++i) {
            int q = i * 256 + tid;
            int m = q >> 4, kq = q & 15;       // m < 64
            *(float4*)&Ws[m][kq * 4] =
                *(const float4*)&Wt[(size_t)(kc + m) * 192 + nb * 64 + kq * 4];
        }
        __syncthreads();
        #pragma unroll
        for (int k4 = 0; k4 < 64; k4 += 4) {
            float4 a4[6], b4[4];
            #pragma unroll
            for (int i = 0; i < 6; ++i) a4[i] = *(const float4*)&As[tr * 6 + i][k4];
            #pragma unroll
            for (int kk = 0; kk < 4; ++kk) b4[kk] = *(const float4*)&Ws[k4 + kk][tc * 4];
            #pragma unroll
            for (int i = 0; i < 6; ++i) {
                const float av[4] = {a4[i].x, a4[i].y, a4[i].z, a4[i].w};
                #pragma unroll
                for (int kk = 0; kk < 4; ++kk) {
                    acc[i].x += av[kk] * b4[kk].x;
                    acc[i].y += av[kk] * b4[kk].y;
                    acc[i].z += av[kk] * b4[kk].z;
                    acc[i].w += av[kk] * b4[kk].w;
                }
            }
        }
        __syncthreads();
    }

    #pragma unroll
    for (int i = 0; i < 6; ++i) {
        int n = n0 + tr * 6 + i;
        int row = b * 576 + n;
        int oc0 = nb * 64 + tc * 4;
        float v[4] = {acc[i].x, acc[i].y, acc[i].z, acc[i].w};
        #pragma unroll
        for (int j = 0; j < 4; ++j) {
            int oc = oc0 + j;
            v[j] = v[j] + sb[oc] + pos[oc * 576 + n];
        }
        *(float4*)&nf[(size_t)row * 192 + oc0] = float4{v[0], v[1], v[2], v[3]};
    }
}

// ---------------- sq norms per node (UNCHANGED) ----------------
__global__ __launch_bounds__(256) void sq_k(const float* __restrict__ nf,
                                            float* __restrict__ sq) {
    int wid = threadIdx.x >> 6, lane = threadIdx.x & 63;
    int n = blockIdx.x * 4 + wid;
    const float* row = nf + (size_t)n * 192;
    float s = 0.f;
    #pragma unroll
    for (int c = 0; c < 3; ++c) { float v = row[lane + c * 64]; s += v * v; }
    #pragma unroll
    for (int off = 32; off; off >>= 1) s += __shfl_down(s, off);
    if (lane == 0) sq[n] = s;
}

// ---------------- transpose nf per image (UNCHANGED) ----------------
__global__ void transpose_nf_k(const float* __restrict__ nf, float* __restrict__ nfT) {
    __shared__ float tile[32][33];
    int b = blockIdx.z;
    int n0 = blockIdx.x * 32, c0 = blockIdx.y * 32;
    int tx = threadIdx.x, ty = threadIdx.y;   // 32 x 8
    #pragma unroll
    for (int r = 0; r < 4; ++r) {
        int i = ty * 4 + r;
        tile[i][tx] = nf[((size_t)b * 576 + n0 + i) * 192 + c0 + tx];
    }
    __syncthreads();
    #pragma unroll
    for (int r = 0; r < 4; ++r) {
        int i = ty * 4 + r;
        nfT[((size_t)b * 192 + c0 + i) * 576 + n0 + tx] = tile[tx][i];
    }
}

// ---------------- kNN: Gram tile + parallel top-5 selection ----------------
// GEMM loops + d2 epilogue are textually IDENTICAL to R1 (bit-sensitive).
// Selection is parallelized (exact same semantics on identical d2 values):
// wave p scans cols [16p,16p+16) ascending -> local lex-sorted top-5;
// parts merge via LDS in (p asc, q asc) order == ascending col index among
// equal values -> identical tie-break to lax.top_k.
__global__ __launch_bounds__(256) void knn_topk_k(
    const float* __restrict__ nf, const float* __restrict__ nfT,
    const float* __restrict__ sqn, int* __restrict__ idxOut)
{
    __shared__ float As[64][68];
    __shared__ float Cs[64][68];
    __shared__ float d2s[64][69];     // stride 69: conflict-free row reads
    const int tid = threadIdx.x;
    const int tr = tid >> 4, tc = tid & 15;
    const int b = blockIdx.x;
    const int row0 = blockIdx.y * 64;

    float* mergeV = (float*)&As[0][0];   // 64 x 21 floats (reused, stale space)
    int*   mergeI = (int*)&Cs[0][0];     // 64 x 21 ints

    float tv[5];
    int ti[5];
    #pragma unroll
    for (int p = 0; p < 5; ++p) { tv[p] = 3.4e38f; ti[p] = 0; }

    for (int cc = 0; cc < 9; ++cc) {
        float4 acc[4];
        acc[0] = acc[1] = acc[2] = acc[3] = float4{0.f, 0.f, 0.f, 0.f};
        for (int kc = 0; kc < 192; kc += 64) {
            #pragma unroll
            for (int i = 0; i < 4; ++i) {
                int q = i * 256 + tid;
                int m = q >> 4, kq = q & 15;
                *(float4*)&As[m][kq * 4] =
                    *(const float4*)&nf[((size_t)(b * 576 + row0 + m)) * 192 + kc + kq * 4];
                *(float4*)&Cs[m][kq * 4] =
                    *(const float4*)&nfT[((size_t)(b * 192 + kc + m)) * 576 + cc * 64 + kq * 4];
            }
            __syncthreads();
            #pragma unroll
            for (int k4 = 0; k4 < 64; k4 += 4) {
                float4 a4[4], b4[4];
                #pragma unroll
                for (int i = 0; i < 4; ++i) a4[i] = *(const float4*)&As[tr * 4 + i][k4];
                #pragma unroll
                for (int kk = 0; kk < 4; ++kk) b4[kk] = *(const float4*)&Cs[k4 + kk][tc * 4];
                #pragma unroll
                for (int i = 0; i < 4; ++i) {
                    const float av[4] = {a4[i].x, a4[i].y, a4[i].z, a4[i].w};
                    #pragma unroll
                    for (int kk = 0; kk < 4; ++kk) {
                        acc[i].x += av[kk] * b4[kk].x;
                        acc[i].y += av[kk] * b4[kk].y;
                        acc[i].z += av[kk] * b4[kk].z;
                        acc[i].w += av[kk] * b4[kk].w;
                    }
                }
            }
            __syncthreads();
        }
        // d2 = sq_r + sq_c - 2*dot (+1e9 on diagonal), same formula as reference
        #pragma unroll
        for (int i = 0; i < 4; ++i) {
            int rl = tr * 4 + i, rg = row0 + rl;
            float sr = sqn[b * 576 + rg];
            float vv[4] = {acc[i].x, acc[i].y, acc[i].z, acc[i].w};
            #pragma unroll
            for (int j = 0; j < 4; ++j) {
                int cl = tc * 4 + j, cg = cc * 64 + cl;
                float d = sr + sqn[b * 576 + cg] - 2.f * vv[j];
                if (cg == rg) d += 1e9f;
                d2s[rl][cl] = d;
            }
        }
        __syncthreads();

        // ---- parallel selection: part p = tid>>6 scans 16 cols of row tid&63 ----
        {
            const int r = tid & 63, p = tid >> 6;
            float pv[5]; int pi[5];
            #pragma unroll
            for (int q = 0; q < 5; ++q) { pv[q] = 3.4e38f; pi[q] = 0x7fffffff; }
            #pragma unroll
            for (int j = 0; j < 16; ++j) {
                int c = p * 16 + j;
                float cv = d2s[r][c];
                if (cv < pv[4]) {
                    int ci = cc * 64 + c;
                    #pragma unroll
                    for (int q = 0; q < 5; ++q) {       // stable sorted insert (strict <)
                        bool less = cv < pv[q];
                        float nv = less ? pv[q] : cv;
                        int ni   = less ? pi[q] : ci;
                        pv[q] = less ? cv : pv[q];
                        pi[q] = less ? ci : pi[q];
                        cv = nv; ci = ni;
                    }
                }
            }
            #pragma unroll
            for (int q = 0; q < 5; ++q) {
                mergeV[r * 21 + p * 5 + q] = pv[q];
                mergeI[r * 21 + p * 5 + q] = pi[q];
            }
        }
        __syncthreads();
        if (tid < 64) {
            // merge 20 candidates (p asc, q asc == lex order among equals)
            for (int s = 0; s < 20; ++s) {
                float cv = mergeV[tid * 21 + s];
                if (cv < tv[4]) {
                    int cidx = mergeI[tid * 21 + s];
                    #pragma unroll
                    for (int q = 0; q < 5; ++q) {
                        bool less = cv < tv[q];
                        float nv = less ? tv[q] : cv;
                        int ni   = less ? ti[q] : cidx;
                        tv[q] = less ? cv : tv[q];
                        ti[q] = less ? cidx : ti[q];
                        cv = nv; cidx = ni;
                    }
                }
            }
        }
        __syncthreads();
    }
    if (tid < 64) {
        int rg = b * 576 + row0 + tid;
        #pragma unroll
        for (int p = 0; p < 5; ++p) idxOut[rg * 5 + p] = b * 576 + ti[p];
    }
}

// ---------------- generic 64x64-tile f32 GEMM (head) ----------------
// EPI: 0 none, 1 +bias, 2 relu(x+bias), 3 gelu((x+bias)*g+be), 4 res + (x+bias)*g+be
template <int EPI>
__global__ __launch_bounds__(256) void gemm_rm_k(
    const float* __restrict__ A, const float* __restrict__ W, float* __restrict__ out,
    int M, int N, int K,
    const float* __restrict__ bias, const float* __restrict__ gsc,
    const float* __restrict__ gsh, const float* __restrict__ res)
{
    __shared__ float As[64][68];
    __shared__ float Ws[64][68];
    const int tid = threadIdx.x;
    const int tr = tid >> 4, tc = tid & 15;
    const int mBase = blockIdx.x * 64, nBase = blockIdx.y * 64;

    float4 acc[4];
    acc[0] = acc[1] = acc[2] = acc[3] = float4{0.f, 0.f, 0.f, 0.f};

    for (int kc = 0; kc < K; kc += 64) {
        #pragma unroll
        for (int i = 0; i < 4; ++i) {
            int q = i * 256 + tid;
            int m = q >> 4, kq = q & 15;
            *(float4*)&As[m][kq * 4] =
                *(const float4*)&A[(size_t)(mBase + m) * K + kc + kq * 4];
            *(float4*)&Ws[m][kq * 4] =
                *(const float4*)&W[(size_t)(kc + m) * N + nBase + kq * 4];
        }
        __syncthreads();
        #pragma unroll
        for (int k4 = 0; k4 < 64; k4 += 4) {
            float4 a4[4], b4[4];
            #pragma unroll
            for (int i = 0; i < 4; ++i) a4[i] = *(const float4*)&As[tr * 4 + i][k4];
            #pragma unroll
            for (int kk = 0; kk < 4; ++kk) b4[kk] = *(const float4*)&Ws[k4 + kk][tc * 4];
            #pragma unroll
            for (int i = 0; i < 4; ++i) {
                const float av[4] = {a4[i].x, a4[i].y, a4[i].z, a4[i].w};
                #pragma unroll
                for (int kk = 0; kk < 4; ++kk) {
                    acc[i].x += av[kk] * b4[kk].x;
                    acc[i].y += av[kk] * b4[kk].y;
                    acc[i].z += av[kk] * b4[kk].z;
                    acc[i].w += av[kk] * b4[kk].w;
                }
            }
        }
        __syncthreads();
    }

    #pragma unroll
    for (int i = 0; i < 4; ++i) {
        int row = mBase + tr * 4 + i;
        int n0 = nBase + tc * 4;
        float v[4] = {acc[i].x, acc[i].y, acc[i].z, acc[i].w};
        #pragma unroll
        for (int j = 0; j < 4; ++j) {
            int n = n0 + j;
            float xv = v[j];
            if (EPI == 1) xv += bias[n];
            if (EPI == 2) { xv += bias[n]; xv = fmaxf(xv, 0.f); }
            if (EPI == 3) { xv = (xv + bias[n]) * gsc[n] + gsh[n]; xv = gelu_exact(xv); }
            if (EPI == 4) {
                xv = res[(size_t)row * N + n] + (xv + bias[n]) * gsc[n] + gsh[n];
            }
            v[j] = xv;
        }
        *(float4*)&out[(size_t)row * N + n0] = float4{v[0], v[1], v[2], v[3]};
    }
}

// ---------------- bf16 MFMA GEMM: A[M][K] bf16, Bt[N][K] bf16, out bf16 (UNCHANGED) ----------------
template <int EPI>
__global__ __launch_bounds__(256) void gemm_mfma_k(
    const unsigned short* __restrict__ A, const unsigned short* __restrict__ Bt,
    unsigned short* __restrict__ out, int M, int N, int K,
    const float* __restrict__ bias, const float* __restrict__ gsc,
    const float* __restrict__ gsh, const unsigned short* __restrict__ res)
{
    using frag = __attribute__((ext_vector_type(8))) short;
    using facc = __attribute__((ext_vector_type(4))) float;
    __shared__ unsigned short As[64][72];   // [m][k]
    __shared__ unsigned short Bs[64][72];   // [n][k]
    const int tid = threadIdx.x;
    const int wave = tid >> 6, lane = tid & 63;
    const int m16 = lane & 15, quad = lane >> 4;
    const int mBase = blockIdx.x * 64, nBase = blockIdx.y * 64;

    facc zero = {0.f, 0.f, 0.f, 0.f};
    facc acc[4];
    #pragma unroll
    for (int t = 0; t < 4; ++t) acc[t] = zero;

    for (int kc = 0; kc < K; kc += 64) {
        #pragma unroll
        for (int r = 0; r < 2; ++r) {
            int q = r * 256 + tid;            // 0..511
            int row = q >> 3, c8 = (q & 7) * 8;
            *(int4*)&As[row][c8] =
                *(const int4*)&A[(size_t)(mBase + row) * K + kc + c8];
            *(int4*)&Bs[row][c8] =
                *(const int4*)&Bt[(size_t)(nBase + row) * K + kc + c8];
        }
        __syncthreads();
        #pragma unroll
        for (int kk = 0; kk < 64; kk += 32) {
            frag a = *(const frag*)&As[16 * wave + m16][kk + quad * 8];
            #pragma unroll
            for (int t = 0; t < 4; ++t) {
                frag b = *(const frag*)&Bs[t * 16 + m16][kk + quad * 8];
                acc[t] = __builtin_amdgcn_mfma_f32_16x16x32_bf16(a, b, acc[t], 0, 0, 0);
            }
        }
        __syncthreads();
    }

    #pragma unroll
    for (int t = 0; t < 4; ++t) {
        #pragma unroll
        for (int r = 0; r < 4; ++r) {
            int row = mBase + 16 * wave + quad * 4 + r;
            int col = nBase + t * 16 + m16;
            float xv = acc[t][r];
            if (EPI == 2) { xv += bias[col]; xv = fmaxf(xv, 0.f); }
            if (EPI == 3) { xv = (xv + bias[col]) * gsc[col] + gsh[col]; xv = gelu_exact(xv); }
            if (EPI == 4) {
                xv = bf2f(res[(size_t)row * N + col]) + (xv + bias[col]) * gsc[col] + gsh[col];
            }
            out[(size_t)row * N + col] = f2bf(xv);
        }
    }
}

// ---------------- split-bf16 MFMA GEMM (f32-accurate): out f32; EPI 0 none, 1 +bias ----------------
template <int EPI>
__global__ __launch_bounds__(256) void gemm_mfma_split_k(
    const unsigned short* __restrict__ Ah, const unsigned short* __restrict__ Al,
    const unsigned short* __restrict__ Bh, const unsigned short* __restrict__ Bl,
    float* __restrict__ out, int M, int N, int K, const float* __restrict__ bias)
{
    using frag = __attribute__((ext_vector_type(8))) short;
    using facc = __attribute__((ext_vector_type(4))) float;
    __shared__ unsigned short AsH[64][72], AsL[64][72];
    __shared__ unsigned short BsH[64][72], BsL[64][72];
    const int tid = threadIdx.x;
    const int wave = tid >> 6, lane = tid & 63;
    const int m16 = lane & 15, quad = lane >> 4;
    const int mBase = blockIdx.x * 64, nBase = blockIdx.y * 64;

    facc zero = {0.f, 0.f, 0.f, 0.f};
    facc acc[4];
    #pragma unroll
    for (int t = 0; t < 4; ++t) acc[t] = zero;

    for (int kc = 0; kc < K; kc += 64) {
        #pragma unroll
        for (int r = 0; r < 2; ++r) {
            int q = r * 256 + tid;
            int row = q >> 3, c8 = (q & 7) * 8;
            *(int4*)&AsH[row][c8] = *(const int4*)&Ah[(size_t)(mBase + row) * K + kc + c8];
            *(int4*)&AsL[row][c8] = *(const int4*)&Al[(size_t)(mBase + row) * K + kc + c8];
            *(int4*)&BsH[row][c8] = *(const int4*)&Bh[(size_t)(nBase + row) * K + kc + c8];
            *(int4*)&BsL[row][c8] = *(const int4*)&Bl[(size_t)(nBase + row) * K + kc + c8];
        }
        __syncthreads();
        #pragma unroll
        for (int kk = 0; kk < 64; kk += 32) {
            frag ah = *(const frag*)&AsH[16 * wave + m16][kk + quad * 8];
            frag al = *(const frag*)&AsL[16 * wave + m16][kk + quad * 8];
            #pragma unroll
            for (int t = 0; t < 4; ++t) {
                frag bh = *(const frag*)&BsH[t * 16 + m16][kk + quad * 8];
                frag bl = *(const frag*)&BsL[t * 16 + m16][kk + quad * 8];
                acc[t] = __builtin_amdgcn_mfma_f32_16x16x32_bf16(ah, bh, acc[t], 0, 0, 0);
                acc[t] = __builtin_amdgcn_mfma_f32_16x16x32_bf16(ah, bl, acc[t], 0, 0, 0);
                acc[t] = __builtin_amdgcn_mfma_f32_16x16x32_bf16(al, bh, acc[t], 0, 0, 0);
            }
        }
        __syncthreads();
    }

    #pragma unroll
    for (int t = 0; t < 4; ++t) {
        #pragma unroll
        for (int r = 0; r < 4; ++r) {
            int row = mBase + 16 * wave + quad * 4 + r;
            int col = nBase + t * 16 + m16;
            float xv = acc[t][r];
            if (EPI == 1) xv += bias[col];
            out[(size_t)row * N + col] = xv;
        }
    }
}

// ---------------- split prep: f32 -> (hi, lo) bf16 ----------------
__global__ __launch_bounds__(256) void asplit_k(const float* __restrict__ a,
                                                unsigned short* __restrict__ hi,
                                                unsigned short* __restrict__ lo) {
    int g = blockIdx.x * 256 + threadIdx.x;
    float v = a[g];
    unsigned short h = f2bf(v);
    hi[g] = h;
    lo[g] = f2bf(v - bf2f(h));
}

// att_w1 [384][192] -> split-transposed [2][192 n][192 k]
__global__ __launch_bounds__(256) void wsplit_att_k(const float* __restrict__ w,
                                                    unsigned short* __restrict__ hi,
                                                    unsigned short* __restrict__ lo) {
    int gid = blockIdx.x * 256 + threadIdx.x;    // < 73728
    int half = gid / 36864, r = gid % 36864;
    int n = r / 192, k = r % 192;
    float v = w[(size_t)(half * 192 + k) * 192 + n];
    unsigned short h = f2bf(v);
    hi[gid] = h;
    lo[gid] = f2bf(v - bf2f(h));
}

// ---------------- weight prep: f32 [K][N] -> bf16 [N][K] ----------------
__global__ __launch_bounds__(256) void wprep_k(const float* __restrict__ w,
                                               unsigned short* __restrict__ wt,
                                               int K, int N) {
    int gid = blockIdx.x * 256 + threadIdx.x;
    int n = gid / K, k = gid % K;
    wt[gid] = f2bf(w[(size_t)k * N + n]);
}

// ---------------- edge attention (UNCHANGED) ----------------
__global__ __launch_bounds__(256) void edge_att_k(
    const float* __restrict__ hA, const float* __restrict__ hB,
    const int* __restrict__ idx, const float* __restrict__ w2,
    const float* __restrict__ b2, float* __restrict__ att)
{
    int wid = threadIdx.x >> 6, lane = threadIdx.x & 63;
    int e = blockIdx.x * 4 + wid;
    int dst = e / K_;
    int src = idx[e];
    float s = 0.f;
    #pragma unroll
    for (int c0 = 0; c0 < 3; ++c0) {
        int c = lane + c0 * 64;
        float v = hA[(size_t)src * 192 + c] + hB[(size_t)dst * 192 + c];
        v = fmaxf(v, 0.f);
        s += v * w2[c];
    }
    #pragma unroll
    for (int off = 32; off; off >>= 1) s += __shfl_down(s, off);
    if (lane == 0) att[e] = 1.f / (1.f + expf(-(s + b2[0])));
}

// ---------------- message passing, bf16 out (f32 or bf16 in) ----------------
__device__ __forceinline__ float ldv(const float* p, size_t i) { return p[i]; }
__device__ __forceinline__ float ldv(const unsigned short* p, size_t i) { return bf2f(p[i]); }

template <typename TI>
__global__ __launch_bounds__(256) void msg_bf_k(
    const TI* __restrict__ h, const float* __restrict__ att,
    const int* __restrict__ idx, unsigned short* __restrict__ s)
{
    int g = blockIdx.x * 256 + threadIdx.x;  // < BN*192
    int n = g / 192, c = g % 192;
    float acc = ldv(h, (size_t)g);
    #pragma unroll
    for (int p = 0; p < K_; ++p) {
        int sp = idx[n * K_ + p];
        acc += att[n * K_ + p] * ldv(h, (size_t)sp * 192 + c);
    }
    s[g] = f2bf(acc);
}

// ---------------- global average pool over nodes (bf16 in) ----------------
__global__ void pool_bf16_k(const unsigned short* __restrict__ t, float* __restrict__ g) {
    int b = blockIdx.x, c = threadIdx.x;   // 192 threads
    float s = 0.f;
    for (int n = 0; n < 576; ++n) s += bf2f(t[((size_t)b * 576 + n) * 192 + c]);
    g[b * 192 + c] = s * (1.f / 576.f);
}

// ---------------- head reduce (UNCHANGED) ----------------
__global__ __launch_bounds__(256) void head2_k(
    const float* __restrict__ p, const float* __restrict__ w2,
    const float* __restrict__ b2, float* __restrict__ out)
{
    int b = blockIdx.x;
    float s = 0.f;
    for (int j = threadIdx.x; j < 1024; j += 256) s += p[(size_t)b * 1024 + j] * w2[j];
    #pragma unroll
    for (int off = 32; off; off >>= 1) s += __shfl_down(s, off);
    __shared__ float ls[4];
    int wid = threadIdx.x >> 6, lane = threadIdx.x & 63;
    if (lane == 0) ls[wid] = s;
    __syncthreads();
    if (threadIdx.x == 0) out[b] = ls[0] + ls[1] + ls[2] + ls[3] + b2[0];
}

// ---------------- launch ----------------
extern "C" void kernel_launch(void* const* d_in, const int* in_sizes, int n_in,
                              void* d_out, int out_size, void* d_ws, size_t ws_size,
                              hipStream_t stream) {
    const float* x        = (const float*)d_in[0];
    const float* stem_w   = (const float*)d_in[1];
    const float* stem_b   = (const float*)d_in[2];
    const float* pos      = (const float*)d_in[3];
    const float* att_w1   = (const float*)d_in[4];
    const float* att_b1   = (const float*)d_in[5];
    const float* att_w2   = (const float*)d_in[6];
    const float* att_b2   = (const float*)d_in[7];
    const float* gnn_w1   = (const float*)d_in[8];
    const float* gnn_b1   = (const float*)d_in[9];
    const float* gnn_w2   = (const float*)d_in[10];
    const float* gnn_b2   = (const float*)d_in[11];
    const float* ffn_w1   = (const float*)d_in[12];
    const float* ffn_b1   = (const float*)d_in[13];
    const float* ffn_g1   = (const float*)d_in[14];
    const float* ffn_be1  = (const float*)d_in[15];
    const float* ffn_w2   = (const float*)d_in[16];
    const float* ffn_b2   = (const float*)d_in[17];
    const float* ffn_g2   = (const float*)d_in[18];
    const float* ffn_be2  = (const float*)d_in[19];
    const float* pred_w1  = (const float*)d_in[20];
    const float* pred_b1  = (const float*)d_in[21];
    const float* pred_g   = (const float*)d_in[22];
    const float* pred_be  = (const float*)d_in[23];
    const float* pred_w2  = (const float*)d_in[24];
    const float* pred_b2  = (const float*)d_in[25];

    float* ws = (float*)d_ws;
    const size_t RSZ = (size_t)BN_ * C_;          // 7,077,888 floats
    float* R0 = ws;               // nf (f32) — live until msg layer 1
    float* R1 = R0 + RSZ;         // hA (f32) -> [Sb | Hb] bf16
    float* R2 = R1 + RSZ;         // hB (f32) -> [Tb | ToutB] bf16
    float* R3 = R2 + RSZ;         // Wt(stem) -> nfT -> [Ahi|Alo] -> Ub
    float* sqb = R3 + RSZ;        // BN
    int*   idxb = (int*)(sqb + BN_);              // E ints
    float* gb = (float*)(idxb + E_);              // 64*192
    float* pb = gb + 64 * C_;                     // 64*1024
    unsigned short* wg1T = (unsigned short*)(pb + 64 * 1024);  // [192][192]
    unsigned short* wg2T = wg1T + 192 * 192;
    unsigned short* wf1T = wg2T + 192 * 192;      // [768][192]
    unsigned short* wf2T = wf1T + 768 * 192;      // [192][768]
    unsigned short* waHi = wf2T + 192 * 768;      // [2][192][192]
    unsigned short* waLo = waHi + 2 * 192 * 192;

    unsigned short* Sb    = (unsigned short*)R1;             // BN x 192 bf16
    unsigned short* Hb    = (unsigned short*)(R1 + RSZ / 2);
    unsigned short* Tb    = (unsigned short*)R2;
    unsigned short* ToutB = (unsigned short*)(R2 + RSZ / 2);
    unsigned short* Ahi   = (unsigned short*)R3;             // after nfT is dead
    unsigned short* Alo   = Ahi + RSZ;
    unsigned short* Ub    = (unsigned short*)R3;             // FFN u-chunk (after att)

    float* att  = (float*)d_out;                  // E
    float* pred = att + E_;                       // 64

    float* Wt = R3;  // alias: used only by stem before nfT is written

    // 0. bf16 weight prep
    wprep_k<<<144, 256, 0, stream>>>(gnn_w1, wg1T, 192, 192);
    wprep_k<<<144, 256, 0, stream>>>(gnn_w2, wg2T, 192, 192);
    wprep_k<<<576, 256, 0, stream>>>(ffn_w1, wf1T, 192, 768);
    wprep_k<<<576, 256, 0, stream>>>(ffn_w2, wf2T, 768, 192);
    wsplit_att_k<<<288, 256, 0, stream>>>(att_w1, waHi, waLo);

    // 1. stem (96-row tile, bit-identical FMA chain)
    transpose_w_k<<<576, 256, 0, stream>>>(stem_w, Wt);
    stem_gemm96_k<<<dim3(384, 3), 256, 0, stream>>>(x, Wt, stem_b, pos, R0);

    // 2. kNN graph (d2 math frozen; selection parallelized, semantics-exact)
    sq_k<<<BN_ / 4, 256, 0, stream>>>(R0, sqb);
    transpose_nf_k<<<dim3(18, 6, 64), dim3(32, 8), 0, stream>>>(R0, R3);
    knn_topk_k<<<dim3(64, 9), 256, 0, stream>>>(R0, R3, sqb, idxb);

    // 3. edge attention — split-bf16 MFMA (f32-accurate within ~1e-4)
    asplit_k<<<BN_ * C_ / 256, 256, 0, stream>>>(R0, Ahi, Alo);
    gemm_mfma_split_k<0><<<dim3(576, 3), 256, 0, stream>>>(Ahi, Alo,
        waHi, waLo, R1, BN_, 192, 192, nullptr);
    gemm_mfma_split_k<1><<<dim3(576, 3), 256, 0, stream>>>(Ahi, Alo,
        waHi + 36864, waLo + 36864, R2, BN_, 192, 192, att_b1);
    edge_att_k<<<E_ / 4, 256, 0, stream>>>(R1, R2, idxb, att_w2, att_b2, att);

    // 4. GNN layer 1 (bf16 MFMA)
    msg_bf_k<float><<<BN_ * C_ / 256, 256, 0, stream>>>(R0, att, idxb, Sb);
    gemm_mfma_k<2><<<dim3(576, 3), 256, 0, stream>>>(Sb, wg1T, Hb,
        BN_, 192, 192, gnn_b1, nullptr, nullptr, nullptr);
    // 5. GNN layer 2
    msg_bf_k<unsigned short><<<BN_ * C_ / 256, 256, 0, stream>>>(Hb, att, idxb, Sb);
    gemm_mfma_k<2><<<dim3(576, 3), 256, 0, stream>>>(Sb, wg2T, Tb,
        BN_, 192, 192, gnn_b2, nullptr, nullptr, nullptr);

    // 6. FFN in 2 node-chunks of 18432 (u chunk = Ub in R3; Ahi/Alo dead)
    for (int ch = 0; ch < 2; ++ch) {
        const unsigned short* Ain = Tb + (size_t)ch * 18432 * 192;
        unsigned short* Tout = ToutB + (size_t)ch * 18432 * 192;
        gemm_mfma_k<3><<<dim3(288, 12), 256, 0, stream>>>(Ain, wf1T, Ub,
            18432, 768, 192, ffn_b1, ffn_g1, ffn_be1, nullptr);
        gemm_mfma_k<4><<<dim3(288, 3), 256, 0, stream>>>(Ub, wf2T, Tout,
            18432, 192, 768, ffn_b2, ffn_g2, ffn_be2, Ain);
    }

    // 7. pool + head (f32, tiny)
    pool_bf16_k<<<64, 192, 0, stream>>>(ToutB, gb);
    gemm_rm_k<3><<<dim3(1, 16), 256, 0, stream>>>(gb, pred_w1, pb,
        64, 1024, 192, pred_b1, pred_g, pred_be, nullptr);
    head2_k<<<64, 256, 0, stream>>>(pb, pred_w2, pred_b2, pred);
}

// Round 7
// 811.188 us; speedup vs baseline: 1.5976x; 1.0815x over previous
//
#include <hip/hip_runtime.h>
#include <hip/hip_bf16.h>
#include <math.h>

// ---------------- problem constants ----------------
constexpr int B_    = 64;
constexpr int C_    = 192;
constexpr int N_    = 576;    // nodes per image (24x24)
constexpr int BN_   = B_ * N_;      // 36864
constexpr int K_    = 5;
constexpr int E_    = BN_ * K_;     // 184320

__device__ __forceinline__ float gelu_exact(float x) {
    return 0.5f * x * (1.0f + erff(x * 0.70710678118654752440f));
}

__device__ __forceinline__ float bf2f(unsigned short v) {
    return __uint_as_float(((unsigned)v) << 16);
}
__device__ __forceinline__ unsigned short f2bf(float x) {
    __hip_bfloat16 h = __float2bfloat16(x);
    return *(unsigned short*)&h;
}

// ---------------- tiny transpose: stem_w [192][768] -> Wt [768][192] ----------------
__global__ __launch_bounds__(256) void transpose_w_k(const float* __restrict__ w,
                                                     float* __restrict__ wt) {
    int gid = blockIdx.x * 256 + threadIdx.x;      // 147456 total
    int k = gid / 192, oc = gid % 192;
    wt[gid] = w[oc * 768 + k];                     // writes coalesced
}

// ---------------- stem: 96-row tile patch-embed GEMM (UNCHANGED — feeds kNN bits) ----------------
__global__ __launch_bounds__(256) void stem_gemm96_k(
    const float* __restrict__ x, const float* __restrict__ Wt,
    const float* __restrict__ sb, const float* __restrict__ pos,
    float* __restrict__ nf)
{
    __shared__ float As[96][68];
    __shared__ float Ws[64][68];
    const int tid = threadIdx.x;
    const int tr = tid >> 4, tc = tid & 15;
    const int mb = blockIdx.x;          // 0..383 (64 images x 6 tiles of 96)
    const int nb = blockIdx.y;          // 0..2 oc blocks
    const int b  = mb / 6;
    const int n0 = (mb % 6) * 96;       // node offset within image

    float4 acc[6];
    #pragma unroll
    for (int i = 0; i < 6; ++i) acc[i] = float4{0.f, 0.f, 0.f, 0.f};

    for (int kc = 0; kc < 768; kc += 64) {
        #pragma unroll
        for (int i = 0; i < 6; ++i) {
            int q = i * 256 + tid;
            int m = q >> 4, kq = q & 15;       // m < 96
            int k = kc + kq * 4;
            int ci = k >> 8, rem = k & 255, dy = rem >> 4, dx = rem & 15;
            int n = n0 + m, py = n / 24, px = n % 24;
            const float* src = &x[(((size_t)(b * 3 + ci) * 384) + py * 16 + dy) * 384
                                  + px * 16 + dx];
            *(float4*)&As[m][kq * 4] = *(const float4*)src;
        }
        #pragma unroll
        for (int i = 0; i < 4; ++i) {
            int q = i * 256 + tid;
            int m = q >> 4, kq = q & 15;       // m < 64
            *(float4*)&Ws[m][kq * 4] =
                *(const float4*)&Wt[(size_t)(kc + m) * 192 + nb * 64 + kq * 4];
        }
        __syncthreads();
        #pragma unroll
        for (int k4 = 0; k4 < 64; k4 += 4) {
            float4 a4[6], b4[4];
            #pragma unroll
            for (int i = 0; i < 6; ++i) a4[i] = *(const float4*)&As[tr * 6 + i][k4];
            #pragma unroll
            for (int kk = 0; kk < 4; ++kk) b4[kk] = *(const float4*)&Ws[k4 + kk][tc * 4];
            #pragma unroll
            for (int i = 0; i < 6; ++i) {
                const float av[4] = {a4[i].x, a4[i].y, a4[i].z, a4[i].w};
                #pragma unroll
                for (int kk = 0; kk < 4; ++kk) {
                    acc[i].x += av[kk] * b4[kk].x;
                    acc[i].y += av[kk] * b4[kk].y;
                    acc[i].z += av[kk] * b4[kk].z;
                    acc[i].w += av[kk] * b4[kk].w;
                }
            }
        }
        __syncthreads();
    }

    #pragma unroll
    for (int i = 0; i < 6; ++i) {
        int n = n0 + tr * 6 + i;
        int row = b * 576 + n;
        int oc0 = nb * 64 + tc * 4;
        float v[4] = {acc[i].x, acc[i].y, acc[i].z, acc[i].w};
        #pragma unroll
        for (int j = 0; j < 4; ++j) {
            int oc = oc0 + j;
            v[j] = v[j] + sb[oc] + pos[oc * 576 + n];
        }
        *(float4*)&nf[(size_t)row * 192 + oc0] = float4{v[0], v[1], v[2], v[3]};
    }
}

// ---------------- sq norms per node (UNCHANGED) ----------------
__global__ __launch_bounds__(256) void sq_k(const float* __restrict__ nf,
                                            float* __restrict__ sq) {
    int wid = threadIdx.x >> 6, lane = threadIdx.x & 63;
    int n = blockIdx.x * 4 + wid;
    const float* row = nf + (size_t)n * 192;
    float s = 0.f;
    #pragma unroll
    for (int c = 0; c < 3; ++c) { float v = row[lane + c * 64]; s += v * v; }
    #pragma unroll
    for (int off = 32; off; off >>= 1) s += __shfl_down(s, off);
    if (lane == 0) sq[n] = s;
}

// ---------------- transpose nf per image (UNCHANGED) ----------------
__global__ void transpose_nf_k(const float* __restrict__ nf, float* __restrict__ nfT) {
    __shared__ float tile[32][33];
    int b = blockIdx.z;
    int n0 = blockIdx.x * 32, c0 = blockIdx.y * 32;
    int tx = threadIdx.x, ty = threadIdx.y;   // 32 x 8
    #pragma unroll
    for (int r = 0; r < 4; ++r) {
        int i = ty * 4 + r;
        tile[i][tx] = nf[((size_t)b * 576 + n0 + i) * 192 + c0 + tx];
    }
    __syncthreads();
    #pragma unroll
    for (int r = 0; r < 4; ++r) {
        int i = ty * 4 + r;
        nfT[((size_t)b * 192 + c0 + i) * 576 + n0 + tx] = tile[tx][i];
    }
}

// ---------------- kNN part: 3 column-chunks per block, partial top-5 per row ----------------
// GEMM loops + d2 epilogue are textually IDENTICAL to R6 (bit-sensitive).
// Only the cc loop bounds changed (cc0..cc0+3) and the final write emits
// the partial lex-sorted top-5 to global candidate buffers.
__global__ __launch_bounds__(256) void knn_part_k(
    const float* __restrict__ nf, const float* __restrict__ nfT,
    const float* __restrict__ sqn, float* __restrict__ candV,
    int* __restrict__ candI)
{
    __shared__ float As[64][68];
    __shared__ float Cs[64][68];
    __shared__ float d2s[64][69];     // stride 69: conflict-free row reads
    const int tid = threadIdx.x;
    const int tr = tid >> 4, tc = tid & 15;
    const int b = blockIdx.x;
    const int row0 = blockIdx.y * 64;
    const int gz = blockIdx.z;
    const int cc0 = gz * 3;

    float* mergeV = (float*)&As[0][0];   // 64 x 21 floats (reused, stale space)
    int*   mergeI = (int*)&Cs[0][0];     // 64 x 21 ints

    float tv[5];
    int ti[5];
    #pragma unroll
    for (int p = 0; p < 5; ++p) { tv[p] = 3.4e38f; ti[p] = 0; }

    for (int cc = cc0; cc < cc0 + 3; ++cc) {
        float4 acc[4];
        acc[0] = acc[1] = acc[2] = acc[3] = float4{0.f, 0.f, 0.f, 0.f};
        for (int kc = 0; kc < 192; kc += 64) {
            #pragma unroll
            for (int i = 0; i < 4; ++i) {
                int q = i * 256 + tid;
                int m = q >> 4, kq = q & 15;
                *(float4*)&As[m][kq * 4] =
                    *(const float4*)&nf[((size_t)(b * 576 + row0 + m)) * 192 + kc + kq * 4];
                *(float4*)&Cs[m][kq * 4] =
                    *(const float4*)&nfT[((size_t)(b * 192 + kc + m)) * 576 + cc * 64 + kq * 4];
            }
            __syncthreads();
            #pragma unroll
            for (int k4 = 0; k4 < 64; k4 += 4) {
                float4 a4[4], b4[4];
                #pragma unroll
                for (int i = 0; i < 4; ++i) a4[i] = *(const float4*)&As[tr * 4 + i][k4];
                #pragma unroll
                for (int kk = 0; kk < 4; ++kk) b4[kk] = *(const float4*)&Cs[k4 + kk][tc * 4];
                #pragma unroll
                for (int i = 0; i < 4; ++i) {
                    const float av[4] = {a4[i].x, a4[i].y, a4[i].z, a4[i].w};
                    #pragma unroll
                    for (int kk = 0; kk < 4; ++kk) {
                        acc[i].x += av[kk] * b4[kk].x;
                        acc[i].y += av[kk] * b4[kk].y;
                        acc[i].z += av[kk] * b4[kk].z;
                        acc[i].w += av[kk] * b4[kk].w;
                    }
                }
            }
            __syncthreads();
        }
        // d2 = sq_r + sq_c - 2*dot (+1e9 on diagonal), same formula as reference
        #pragma unroll
        for (int i = 0; i < 4; ++i) {
            int rl = tr * 4 + i, rg = row0 + rl;
            float sr = sqn[b * 576 + rg];
            float vv[4] = {acc[i].x, acc[i].y, acc[i].z, acc[i].w};
            #pragma unroll
            for (int j = 0; j < 4; ++j) {
                int cl = tc * 4 + j, cg = cc * 64 + cl;
                float d = sr + sqn[b * 576 + cg] - 2.f * vv[j];
                if (cg == rg) d += 1e9f;
                d2s[rl][cl] = d;
            }
        }
        __syncthreads();

        // ---- parallel selection: part p = tid>>6 scans 16 cols of row tid&63 ----
        {
            const int r = tid & 63, p = tid >> 6;
            float pv[5]; int pi[5];
            #pragma unroll
            for (int q = 0; q < 5; ++q) { pv[q] = 3.4e38f; pi[q] = 0x7fffffff; }
            #pragma unroll
            for (int j = 0; j < 16; ++j) {
                int c = p * 16 + j;
                float cv = d2s[r][c];
                if (cv < pv[4]) {
                    int ci = cc * 64 + c;
                    #pragma unroll
                    for (int q = 0; q < 5; ++q) {       // stable sorted insert (strict <)
                        bool less = cv < pv[q];
                        float nv = less ? pv[q] : cv;
                        int ni   = less ? pi[q] : ci;
                        pv[q] = less ? cv : pv[q];
                        pi[q] = less ? ci : pi[q];
                        cv = nv; ci = ni;
                    }
                }
            }
            #pragma unroll
            for (int q = 0; q < 5; ++q) {
                mergeV[r * 21 + p * 5 + q] = pv[q];
                mergeI[r * 21 + p * 5 + q] = pi[q];
            }
        }
        __syncthreads();
        if (tid < 64) {
            // merge 20 candidates (p asc, q asc == lex order among equals)
            for (int s = 0; s < 20; ++s) {
                float cv = mergeV[tid * 21 + s];
                if (cv < tv[4]) {
                    int cidx = mergeI[tid * 21 + s];
                    #pragma unroll
                    for (int q = 0; q < 5; ++q) {
                        bool less = cv < tv[q];
                        float nv = less ? tv[q] : cv;
                        int ni   = less ? ti[q] : cidx;
                        tv[q] = less ? cv : tv[q];
                        ti[q] = less ? cidx : ti[q];
                        cv = nv; cidx = ni;
                    }
                }
            }
        }
        __syncthreads();
    }
    if (tid < 64) {
        int gr = b * 576 + row0 + tid;
        #pragma unroll
        for (int p = 0; p < 5; ++p) {
            candV[(size_t)gr * 15 + gz * 5 + p] = tv[p];
            candI[(size_t)gr * 15 + gz * 5 + p] = ti[p];
        }
    }
}

// ---------------- kNN merge: 3 groups x 5 sorted candidates -> final top-5 ----------------
// Insert order (group asc, rank asc) preserves lax.top_k lowest-index tie-break.
__global__ __launch_bounds__(256) void knn_merge_k(
    const float* __restrict__ candV, const int* __restrict__ candI,
    int* __restrict__ idxOut)
{
    int r = blockIdx.x * 256 + threadIdx.x;    // < BN_
    float tv[5]; int ti[5];
    #pragma unroll
    for (int p = 0; p < 5; ++p) { tv[p] = 3.4e38f; ti[p] = 0; }
    #pragma unroll
    for (int s = 0; s < 15; ++s) {
        float cv = candV[(size_t)r * 15 + s];
        if (cv < tv[4]) {
            int cidx = candI[(size_t)r * 15 + s];
            #pragma unroll
            for (int q = 0; q < 5; ++q) {
                bool less = cv < tv[q];
                float nv = less ? tv[q] : cv;
                int ni   = less ? ti[q] : cidx;
                tv[q] = less ? cv : tv[q];
                ti[q] = less ? cidx : ti[q];
                cv = nv; cidx = ni;
            }
        }
    }
    int base = (r / 576) * 576;
    #pragma unroll
    for (int p = 0; p < 5; ++p) idxOut[r * 5 + p] = base + ti[p];
}

// ---------------- generic 64x64-tile f32 GEMM (head) ----------------
template <int EPI>
__global__ __launch_bounds__(256) void gemm_rm_k(
    const float* __restrict__ A, const float* __restrict__ W, float* __restrict__ out,
    int M, int N, int K,
    const float* __restrict__ bias, const float* __restrict__ gsc,
    const float* __restrict__ gsh, const float* __restrict__ res)
{
    __shared__ float As[64][68];
    __shared__ float Ws[64][68];
    const int tid = threadIdx.x;
    const int tr = tid >> 4, tc = tid & 15;
    const int mBase = blockIdx.x * 64, nBase = blockIdx.y * 64;

    float4 acc[4];
    acc[0] = acc[1] = acc[2] = acc[3] = float4{0.f, 0.f, 0.f, 0.f};

    for (int kc = 0; kc < K; kc += 64) {
        #pragma unroll
        for (int i = 0; i < 4; ++i) {
            int q = i * 256 + tid;
            int m = q >> 4, kq = q & 15;
            *(float4*)&As[m][kq * 4] =
                *(const float4*)&A[(size_t)(mBase + m) * K + kc + kq * 4];
            *(float4*)&Ws[m][kq * 4] =
                *(const float4*)&W[(size_t)(kc + m) * N + nBase + kq * 4];
        }
        __syncthreads();
        #pragma unroll
        for (int k4 = 0; k4 < 64; k4 += 4) {
            float4 a4[4], b4[4];
            #pragma unroll
            for (int i = 0; i < 4; ++i) a4[i] = *(const float4*)&As[tr * 4 + i][k4];
            #pragma unroll
            for (int kk = 0; kk < 4; ++kk) b4[kk] = *(const float4*)&Ws[k4 + kk][tc * 4];
            #pragma unroll
            for (int i = 0; i < 4; ++i) {
                const float av[4] = {a4[i].x, a4[i].y, a4[i].z, a4[i].w};
                #pragma unroll
                for (int kk = 0; kk < 4; ++kk) {
                    acc[i].x += av[kk] * b4[kk].x;
                    acc[i].y += av[kk] * b4[kk].y;
                    acc[i].z += av[kk] * b4[kk].z;
                    acc[i].w += av[kk] * b4[kk].w;
                }
            }
        }
        __syncthreads();
    }

    #pragma unroll
    for (int i = 0; i < 4; ++i) {
        int row = mBase + tr * 4 + i;
        int n0 = nBase + tc * 4;
        float v[4] = {acc[i].x, acc[i].y, acc[i].z, acc[i].w};
        #pragma unroll
        for (int j = 0; j < 4; ++j) {
            int n = n0 + j;
            float xv = v[j];
            if (EPI == 1) xv += bias[n];
            if (EPI == 2) { xv += bias[n]; xv = fmaxf(xv, 0.f); }
            if (EPI == 3) { xv = (xv + bias[n]) * gsc[n] + gsh[n]; xv = gelu_exact(xv); }
            if (EPI == 4) {
                xv = res[(size_t)row * N + n] + (xv + bias[n]) * gsc[n] + gsh[n];
            }
            v[j] = xv;
        }
        *(float4*)&out[(size_t)row * N + n0] = float4{v[0], v[1], v[2], v[3]};
    }
}

// ---------------- bf16 MFMA GEMM (UNCHANGED) ----------------
template <int EPI>
__global__ __launch_bounds__(256) void gemm_mfma_k(
    const unsigned short* __restrict__ A, const unsigned short* __restrict__ Bt,
    unsigned short* __restrict__ out, int M, int N, int K,
    const float* __restrict__ bias, const float* __restrict__ gsc,
    const float* __restrict__ gsh, const unsigned short* __restrict__ res)
{
    using frag = __attribute__((ext_vector_type(8))) short;
    using facc = __attribute__((ext_vector_type(4))) float;
    __shared__ unsigned short As[64][72];   // [m][k]
    __shared__ unsigned short Bs[64][72];   // [n][k]
    const int tid = threadIdx.x;
    const int wave = tid >> 6, lane = tid & 63;
    const int m16 = lane & 15, quad = lane >> 4;
    const int mBase = blockIdx.x * 64, nBase = blockIdx.y * 64;

    facc zero = {0.f, 0.f, 0.f, 0.f};
    facc acc[4];
    #pragma unroll
    for (int t = 0; t < 4; ++t) acc[t] = zero;

    for (int kc = 0; kc < K; kc += 64) {
        #pragma unroll
        for (int r = 0; r < 2; ++r) {
            int q = r * 256 + tid;            // 0..511
            int row = q >> 3, c8 = (q & 7) * 8;
            *(int4*)&As[row][c8] =
                *(const int4*)&A[(size_t)(mBase + row) * K + kc + c8];
            *(int4*)&Bs[row][c8] =
                *(const int4*)&Bt[(size_t)(nBase + row) * K + kc + c8];
        }
        __syncthreads();
        #pragma unroll
        for (int kk = 0; kk < 64; kk += 32) {
            frag a = *(const frag*)&As[16 * wave + m16][kk + quad * 8];
            #pragma unroll
            for (int t = 0; t < 4; ++t) {
                frag b = *(const frag*)&Bs[t * 16 + m16][kk + quad * 8];
                acc[t] = __builtin_amdgcn_mfma_f32_16x16x32_bf16(a, b, acc[t], 0, 0, 0);
            }
        }
        __syncthreads();
    }

    #pragma unroll
    for (int t = 0; t < 4; ++t) {
        #pragma unroll
        for (int r = 0; r < 4; ++r) {
            int row = mBase + 16 * wave + quad * 4 + r;
            int col = nBase + t * 16 + m16;
            float xv = acc[t][r];
            if (EPI == 2) { xv += bias[col]; xv = fmaxf(xv, 0.f); }
            if (EPI == 3) { xv = (xv + bias[col]) * gsc[col] + gsh[col]; xv = gelu_exact(xv); }
            if (EPI == 4) {
                xv = bf2f(res[(size_t)row * N + col]) + (xv + bias[col]) * gsc[col] + gsh[col];
            }
            out[(size_t)row * N + col] = f2bf(xv);
        }
    }
}

// ---------------- split-bf16 MFMA GEMM (UNCHANGED) ----------------
template <int EPI>
__global__ __launch_bounds__(256) void gemm_mfma_split_k(
    const unsigned short* __restrict__ Ah, const unsigned short* __restrict__ Al,
    const unsigned short* __restrict__ Bh, const unsigned short* __restrict__ Bl,
    float* __restrict__ out, int M, int N, int K, const float* __restrict__ bias)
{
    using frag = __attribute__((ext_vector_type(8))) short;
    using facc = __attribute__((ext_vector_type(4))) float;
    __shared__ unsigned short AsH[64][72], AsL[64][72];
    __shared__ unsigned short BsH[64][72], BsL[64][72];
    const int tid = threadIdx.x;
    const int wave = tid >> 6, lane = tid & 63;
    const int m16 = lane & 15, quad = lane >> 4;
    const int mBase = blockIdx.x * 64, nBase = blockIdx.y * 64;

    facc zero = {0.f, 0.f, 0.f, 0.f};
    facc acc[4];
    #pragma unroll
    for (int t = 0; t < 4; ++t) acc[t] = zero;

    for (int kc = 0; kc < K; kc += 64) {
        #pragma unroll
        for (int r = 0; r < 2; ++r) {
            int q = r * 256 + tid;
            int row = q >> 3, c8 = (q & 7) * 8;
            *(int4*)&AsH[row][c8] = *(const int4*)&Ah[(size_t)(mBase + row) * K + kc + c8];
            *(int4*)&AsL[row][c8] = *(const int4*)&Al[(size_t)(mBase + row) * K + kc + c8];
            *(int4*)&BsH[row][c8] = *(const int4*)&Bh[(size_t)(nBase + row) * K + kc + c8];
            *(int4*)&BsL[row][c8] = *(const int4*)&Bl[(size_t)(nBase + row) * K + kc + c8];
        }
        __syncthreads();
        #pragma unroll
        for (int kk = 0; kk < 64; kk += 32) {
            frag ah = *(const frag*)&AsH[16 * wave + m16][kk + quad * 8];
            frag al = *(const frag*)&AsL[16 * wave + m16][kk + quad * 8];
            #pragma unroll
            for (int t = 0; t < 4; ++t) {
                frag bh = *(const frag*)&BsH[t * 16 + m16][kk + quad * 8];
                frag bl = *(const frag*)&BsL[t * 16 + m16][kk + quad * 8];
                acc[t] = __builtin_amdgcn_mfma_f32_16x16x32_bf16(ah, bh, acc[t], 0, 0, 0);
                acc[t] = __builtin_amdgcn_mfma_f32_16x16x32_bf16(ah, bl, acc[t], 0, 0, 0);
                acc[t] = __builtin_amdgcn_mfma_f32_16x16x32_bf16(al, bh, acc[t], 0, 0, 0);
            }
        }
        __syncthreads();
    }

    #pragma unroll
    for (int t = 0; t < 4; ++t) {
        #pragma unroll
        for (int r = 0; r < 4; ++r) {
            int row = mBase + 16 * wave + quad * 4 + r;
            int col = nBase + t * 16 + m16;
            float xv = acc[t][r];
            if (EPI == 1) xv += bias[col];
            out[(size_t)row * N + col] = xv;
        }
    }
}

// ---------------- split prep: f32 -> (hi, lo) bf16 ----------------
__global__ __launch_bounds__(256) void asplit_k(const float* __restrict__ a,
                                                unsigned short* __restrict__ hi,
                                                unsigned short* __restrict__ lo) {
    int g = blockIdx.x * 256 + threadIdx.x;
    float v = a[g];
    unsigned short h = f2bf(v);
    hi[g] = h;
    lo[g] = f2bf(v - bf2f(h));
}

// att_w1 [384][192] -> split-transposed [2][192 n][192 k]
__global__ __launch_bounds__(256) void wsplit_att_k(const float* __restrict__ w,
                                                    unsigned short* __restrict__ hi,
                                                    unsigned short* __restrict__ lo) {
    int gid = blockIdx.x * 256 + threadIdx.x;    // < 73728
    int half = gid / 36864, r = gid % 36864;
    int n = r / 192, k = r % 192;
    float v = w[(size_t)(half * 192 + k) * 192 + n];
    unsigned short h = f2bf(v);
    hi[gid] = h;
    lo[gid] = f2bf(v - bf2f(h));
}

// ---------------- weight prep: f32 [K][N] -> bf16 [N][K] ----------------
__global__ __launch_bounds__(256) void wprep_k(const float* __restrict__ w,
                                               unsigned short* __restrict__ wt,
                                               int K, int N) {
    int gid = blockIdx.x * 256 + threadIdx.x;
    int n = gid / K, k = gid % K;
    wt[gid] = f2bf(w[(size_t)k * N + n]);
}

// ---------------- edge attention (UNCHANGED) ----------------
__global__ __launch_bounds__(256) void edge_att_k(
    const float* __restrict__ hA, const float* __restrict__ hB,
    const int* __restrict__ idx, const float* __restrict__ w2,
    const float* __restrict__ b2, float* __restrict__ att)
{
    int wid = threadIdx.x >> 6, lane = threadIdx.x & 63;
    int e = blockIdx.x * 4 + wid;
    int dst = e / K_;
    int src = idx[e];
    float s = 0.f;
    #pragma unroll
    for (int c0 = 0; c0 < 3; ++c0) {
        int c = lane + c0 * 64;
        float v = hA[(size_t)src * 192 + c] + hB[(size_t)dst * 192 + c];
        v = fmaxf(v, 0.f);
        s += v * w2[c];
    }
    #pragma unroll
    for (int off = 32; off; off >>= 1) s += __shfl_down(s, off);
    if (lane == 0) att[e] = 1.f / (1.f + expf(-(s + b2[0])));
}

// ---------------- message passing, bf16 out (f32 or bf16 in) ----------------
__device__ __forceinline__ float ldv(const float* p, size_t i) { return p[i]; }
__device__ __forceinline__ float ldv(const unsigned short* p, size_t i) { return bf2f(p[i]); }

template <typename TI>
__global__ __launch_bounds__(256) void msg_bf_k(
    const TI* __restrict__ h, const float* __restrict__ att,
    const int* __restrict__ idx, unsigned short* __restrict__ s)
{
    int g = blockIdx.x * 256 + threadIdx.x;  // < BN*192
    int n = g / 192, c = g % 192;
    float acc = ldv(h, (size_t)g);
    #pragma unroll
    for (int p = 0; p < K_; ++p) {
        int sp = idx[n * K_ + p];
        acc += att[n * K_ + p] * ldv(h, (size_t)sp * 192 + c);
    }
    s[g] = f2bf(acc);
}

// ---------------- global average pool over nodes (bf16 in) ----------------
__global__ void pool_bf16_k(const unsigned short* __restrict__ t, float* __restrict__ g) {
    int b = blockIdx.x, c = threadIdx.x;   // 192 threads
    float s = 0.f;
    for (int n = 0; n < 576; ++n) s += bf2f(t[((size_t)b * 576 + n) * 192 + c]);
    g[b * 192 + c] = s * (1.f / 576.f);
}

// ---------------- head reduce (UNCHANGED) ----------------
__global__ __launch_bounds__(256) void head2_k(
    const float* __restrict__ p, const float* __restrict__ w2,
    const float* __restrict__ b2, float* __restrict__ out)
{
    int b = blockIdx.x;
    float s = 0.f;
    for (int j = threadIdx.x; j < 1024; j += 256) s += p[(size_t)b * 1024 + j] * w2[j];
    #pragma unroll
    for (int off = 32; off; off >>= 1) s += __shfl_down(s, off);
    __shared__ float ls[4];
    int wid = threadIdx.x >> 6, lane = threadIdx.x & 63;
    if (lane == 0) ls[wid] = s;
    __syncthreads();
    if (threadIdx.x == 0) out[b] = ls[0] + ls[1] + ls[2] + ls[3] + b2[0];
}

// ---------------- launch ----------------
extern "C" void kernel_launch(void* const* d_in, const int* in_sizes, int n_in,
                              void* d_out, int out_size, void* d_ws, size_t ws_size,
                              hipStream_t stream) {
    const float* x        = (const float*)d_in[0];
    const float* stem_w   = (const float*)d_in[1];
    const float* stem_b   = (const float*)d_in[2];
    const float* pos      = (const float*)d_in[3];
    const float* att_w1   = (const float*)d_in[4];
    const float* att_b1   = (const float*)d_in[5];
    const float* att_w2   = (const float*)d_in[6];
    const float* att_b2   = (const float*)d_in[7];
    const float* gnn_w1   = (const float*)d_in[8];
    const float* gnn_b1   = (const float*)d_in[9];
    const float* gnn_w2   = (const float*)d_in[10];
    const float* gnn_b2   = (const float*)d_in[11];
    const float* ffn_w1   = (const float*)d_in[12];
    const float* ffn_b1   = (const float*)d_in[13];
    const float* ffn_g1   = (const float*)d_in[14];
    const float* ffn_be1  = (const float*)d_in[15];
    const float* ffn_w2   = (const float*)d_in[16];
    const float* ffn_b2   = (const float*)d_in[17];
    const float* ffn_g2   = (const float*)d_in[18];
    const float* ffn_be2  = (const float*)d_in[19];
    const float* pred_w1  = (const float*)d_in[20];
    const float* pred_b1  = (const float*)d_in[21];
    const float* pred_g   = (const float*)d_in[22];
    const float* pred_be  = (const float*)d_in[23];
    const float* pred_w2  = (const float*)d_in[24];
    const float* pred_b2  = (const float*)d_in[25];

    float* ws = (float*)d_ws;
    const size_t RSZ = (size_t)BN_ * C_;          // 7,077,888 floats
    float* R0 = ws;               // nf (f32) — live until msg layer 1
    float* R1 = R0 + RSZ;         // hA (f32) -> [Sb | Hb] bf16
    float* R2 = R1 + RSZ;         // hB (f32) -> [Tb | ToutB] bf16
    float* R3 = R2 + RSZ;         // Wt(stem) -> nfT -> [Ahi|Alo] -> Ub
    float* sqb = R3 + RSZ;        // BN
    int*   idxb = (int*)(sqb + BN_);              // E ints
    float* gb = (float*)(idxb + E_);              // 64*192
    float* pb = gb + 64 * C_;                     // 64*1024
    unsigned short* wg1T = (unsigned short*)(pb + 64 * 1024);  // [192][192]
    unsigned short* wg2T = wg1T + 192 * 192;
    unsigned short* wf1T = wg2T + 192 * 192;      // [768][192]
    unsigned short* wf2T = wf1T + 768 * 192;      // [192][768]
    unsigned short* waHi = wf2T + 192 * 768;      // [2][192][192]
    unsigned short* waLo = waHi + 2 * 192 * 192;
    float* candV = (float*)(waLo + 2 * 192 * 192);       // BN x 15
    int*   candI = (int*)(candV + (size_t)BN_ * 15);     // BN x 15

    unsigned short* Sb    = (unsigned short*)R1;             // BN x 192 bf16
    unsigned short* Hb    = (unsigned short*)(R1 + RSZ / 2);
    unsigned short* Tb    = (unsigned short*)R2;
    unsigned short* ToutB = (unsigned short*)(R2 + RSZ / 2);
    unsigned short* Ahi   = (unsigned short*)R3;             // after nfT is dead
    unsigned short* Alo   = Ahi + RSZ;
    unsigned short* Ub    = (unsigned short*)R3;             // FFN u-chunk (after att)

    float* att  = (float*)d_out;                  // E
    float* pred = att + E_;                       // 64

    float* Wt = R3;  // alias: used only by stem before nfT is written

    // 0. bf16 weight prep
    wprep_k<<<144, 256, 0, stream>>>(gnn_w1, wg1T, 192, 192);
    wprep_k<<<144, 256, 0, stream>>>(gnn_w2, wg2T, 192, 192);
    wprep_k<<<576, 256, 0, stream>>>(ffn_w1, wf1T, 192, 768);
    wprep_k<<<576, 256, 0, stream>>>(ffn_w2, wf2T, 768, 192);
    wsplit_att_k<<<288, 256, 0, stream>>>(att_w1, waHi, waLo);

    // 1. stem (96-row tile, bit-identical FMA chain)
    transpose_w_k<<<576, 256, 0, stream>>>(stem_w, Wt);
    stem_gemm96_k<<<dim3(384, 3), 256, 0, stream>>>(x, Wt, stem_b, pos, R0);

    // 2. kNN graph (d2 math frozen; 3-way cc split + exact merge)
    sq_k<<<BN_ / 4, 256, 0, stream>>>(R0, sqb);
    transpose_nf_k<<<dim3(18, 6, 64), dim3(32, 8), 0, stream>>>(R0, R3);
    knn_part_k<<<dim3(64, 9, 3), 256, 0, stream>>>(R0, R3, sqb, candV, candI);
    knn_merge_k<<<BN_ / 256, 256, 0, stream>>>(candV, candI, idxb);

    // 3. edge attention — split-bf16 MFMA (f32-accurate within ~1e-4)
    asplit_k<<<BN_ * C_ / 256, 256, 0, stream>>>(R0, Ahi, Alo);
    gemm_mfma_split_k<0><<<dim3(576, 3), 256, 0, stream>>>(Ahi, Alo,
        waHi, waLo, R1, BN_, 192, 192, nullptr);
    gemm_mfma_split_k<1><<<dim3(576, 3), 256, 0, stream>>>(Ahi, Alo,
        waHi + 36864, waLo + 36864, R2, BN_, 192, 192, att_b1);
    edge_att_k<<<E_ / 4, 256, 0, stream>>>(R1, R2, idxb, att_w2, att_b2, att);

    // 4. GNN layer 1 (bf16 MFMA)
    msg_bf_k<float><<<BN_ * C_ / 256, 256, 0, stream>>>(R0, att, idxb, Sb);
    gemm_mfma_k<2><<<dim3(576, 3), 256, 0, stream>>>(Sb, wg1T, Hb,
        BN_, 192, 192, gnn_b1, nullptr, nullptr, nullptr);
    // 5. GNN layer 2
    msg_bf_k<unsigned short><<<BN_ * C_ / 256, 256, 0, stream>>>(Hb, att, idxb, Sb);
    gemm_mfma_k<2><<<dim3(576, 3), 256, 0, stream>>>(Sb, wg2T, Tb,
        BN_, 192, 192, gnn_b2, nullptr, nullptr, nullptr);

    // 6. FFN in 2 node-chunks of 18432 (u chunk = Ub in R3; Ahi/Alo dead)
    for (int ch = 0; ch < 2; ++ch) {
        const unsigned short* Ain = Tb + (size_t)ch * 18432 * 192;
        unsigned short* Tout = ToutB + (size_t)ch * 18432 * 192;
        gemm_mfma_k<3><<<dim3(288, 12), 256, 0, stream>>>(Ain, wf1T, Ub,
            18432, 768, 192, ffn_b1, ffn_g1, ffn_be1, nullptr);
        gemm_mfma_k<4><<<dim3(288, 3), 256, 0, stream>>>(Ub, wf2T, Tout,
            18432, 192, 768, ffn_b2, ffn_g2, ffn_be2, Ain);
    }

    // 7. pool + head (f32, tiny)
    pool_bf16_k<<<64, 192, 0, stream>>>(ToutB, gb);
    gemm_rm_k<3><<<dim3(1, 16), 256, 0, stream>>>(gb, pred_w1, pb,
        64, 1024, 192, pred_b1, pred_g, pred_be, nullptr);
    head2_k<<<64, 256, 0, stream>>>(pb, pred_w2, pred_b2, pred);
}